// Round 1
// baseline (172.575 us; speedup 1.0000x reference)
//
#include <hip/hip_runtime.h>
#include <stdint.h>

// Problem constants
#define B_ 2
#define S_ 2048
#define H_ 1024
#define NH_ 16
#define HD_ 64
#define M_ 4096            // B*S
#define LORA_SCALE 4.0f

typedef unsigned short u16;
typedef __bf16 bf16x8 __attribute__((ext_vector_type(8)));
typedef float  f32x4  __attribute__((ext_vector_type(4)));

__device__ inline u16 f2bf(float f) {
  union { float f; uint32_t u; } a; a.f = f;
  uint32_t r = a.u + 0x7FFFu + ((a.u >> 16) & 1u);
  return (u16)(r >> 16);
}

__device__ inline void gload_lds16(const void* g, void* l) {
  __builtin_amdgcn_global_load_lds((const __attribute__((address_space(1))) void*)g,
                                   (__attribute__((address_space(3))) void*)l, 16, 0, 0);
}

// ---------------- Kernel 1: f32 -> bf16 convert (x and Wq/Wk/Wv) ----------------
__global__ __launch_bounds__(256) void cvt_kernel(
    const float* __restrict__ x,
    const float* __restrict__ wq, const float* __restrict__ wk, const float* __restrict__ wv,
    u16* __restrict__ xbf, u16* __restrict__ wbf) {
  const int XN = M_ * H_;            // 4194304
  const int WN = H_ * H_;            // 1048576
  const int total = XN + 3 * WN;
  int idx = (blockIdx.x * 256 + threadIdx.x) * 4;
  for (; idx < total; idx += gridDim.x * 256 * 4) {
    const float* src; u16* dst; int off;
    if (idx < XN) { src = x; dst = xbf; off = idx; }
    else {
      int j = idx - XN; int p = j >> 20; off = j & (WN - 1);
      src = (p == 0) ? wq : (p == 1 ? wk : wv);
      dst = wbf + (p << 20);
    }
    float4 v = *(const float4*)(src + off);
    *(ushort4*)(dst + off) = make_ushort4(f2bf(v.x), f2bf(v.y), f2bf(v.z), f2bf(v.w));
  }
}

// ---------------- Kernel 2: LoRA down-proj xa[p][m][r] = x[m,:].A_p[r,:] (f32) ----------------
__global__ __launch_bounds__(256) void xa_kernel(
    const float* __restrict__ x,
    const float* __restrict__ Aq, const float* __restrict__ Ak, const float* __restrict__ Av,
    float* __restrict__ xa) {
  const int w = threadIdx.x >> 6, lane = threadIdx.x & 63;
  const int m = blockIdx.x * 4 + w;
  float xv[16];
#pragma unroll
  for (int j = 0; j < 16; ++j) xv[j] = x[m * 1024 + j * 64 + lane];
  const float* Ap[3] = {Aq, Ak, Av};
  float s[12];
#pragma unroll
  for (int p = 0; p < 3; ++p) {
#pragma unroll
    for (int r = 0; r < 4; ++r) {
      const float* Ar = Ap[p] + r * 1024;
      float acc = 0.f;
#pragma unroll
      for (int j = 0; j < 16; ++j) acc += xv[j] * Ar[j * 64 + lane];
      s[p * 4 + r] = acc;
    }
  }
#pragma unroll
  for (int i = 0; i < 12; ++i) {
    float v = s[i];
#pragma unroll
    for (int off = 32; off >= 1; off >>= 1) v += __shfl_xor(v, off, 64);
    s[i] = v;
  }
  if (lane == 0) {
#pragma unroll
    for (int p = 0; p < 3; ++p)
#pragma unroll
      for (int r = 0; r < 4; ++r)
        xa[(p * M_ + m) * 4 + r] = s[p * 4 + r];
  }
}

// ---------------- Kernel 3: fused QKV GEMM (bf16 MFMA) + bias + LoRA-up epilogue ----------------
// out[m,n] = sum_k x[m,k] W_p[n,k] + b_p[n] + 4.0 * sum_r xa[p][m][r] * LB_p[n][r]
// Writes bf16 into qkv[p][bh][s][d]; Q pre-scaled by 1/8 (exact in bf16).
__global__ __launch_bounds__(256) void qkv_gemm(
    const u16* __restrict__ xbf, const u16* __restrict__ wbf,
    const float* __restrict__ bq, const float* __restrict__ bk, const float* __restrict__ bv,
    const float* __restrict__ lbq, const float* __restrict__ lbk, const float* __restrict__ lbv,
    const float* __restrict__ xa, u16* __restrict__ qkv) {
  const int p  = blockIdx.z;
  const int n0 = blockIdx.x * 128;
  const int m0 = blockIdx.y * 128;
  const u16* Wp = wbf + (p << 20);
  const float* bias = (p == 0) ? bq : (p == 1 ? bk : bv);
  const float* LB   = (p == 0) ? lbq : (p == 1 ? lbk : lbv);
  __shared__ __align__(16) u16 As[128 * 32];
  __shared__ __align__(16) u16 Bs[128 * 32];
  const int tid = threadIdx.x, lane = tid & 63, w = tid >> 6;
  const int g = lane >> 4, q15 = lane & 15;
  const int wr = w >> 1, wc = w & 1;
  const f32x4 fzero = {0.f, 0.f, 0.f, 0.f};
  f32x4 acc[4][4];
#pragma unroll
  for (int mi = 0; mi < 4; ++mi)
#pragma unroll
    for (int ni = 0; ni < 4; ++ni) acc[mi][ni] = fzero;
  const int srow = lane >> 2, scol = (lane & 3) * 8;

  for (int k0 = 0; k0 < 1024; k0 += 32) {
#pragma unroll
    for (int j = 0; j < 2; ++j) {
      int c = w * 2 + j;
      int row = c * 16 + srow;
      gload_lds16(xbf + (m0 + row) * 1024 + k0 + scol, As + c * 512);
      gload_lds16(Wp  + (n0 + row) * 1024 + k0 + scol, Bs + c * 512);
    }
    __syncthreads();
    bf16x8 af[4], bfr[4];
#pragma unroll
    for (int mi = 0; mi < 4; ++mi)
      af[mi] = *(const bf16x8*)&As[(wr * 64 + mi * 16 + q15) * 32 + g * 8];
#pragma unroll
    for (int ni = 0; ni < 4; ++ni)
      bfr[ni] = *(const bf16x8*)&Bs[(wc * 64 + ni * 16 + q15) * 32 + g * 8];
#pragma unroll
    for (int mi = 0; mi < 4; ++mi)
#pragma unroll
      for (int ni = 0; ni < 4; ++ni)
        acc[mi][ni] = __builtin_amdgcn_mfma_f32_16x16x32_bf16(af[mi], bfr[ni], acc[mi][ni], 0, 0, 0);
    __syncthreads();
  }

  // epilogue
  float biasv[4]; f32x4 lbv4[4];
#pragma unroll
  for (int ni = 0; ni < 4; ++ni) {
    int n = n0 + wc * 64 + ni * 16 + q15;
    biasv[ni] = bias[n];
    lbv4[ni] = *(const f32x4*)&LB[n * 4];
  }
#pragma unroll
  for (int mi = 0; mi < 4; ++mi) {
#pragma unroll
    for (int r = 0; r < 4; ++r) {
      int m = m0 + wr * 64 + mi * 16 + g * 4 + r;
      f32x4 xv = *(const f32x4*)&xa[(p * M_ + m) * 4];
      int b = m >> 11, s = m & 2047;
#pragma unroll
      for (int ni = 0; ni < 4; ++ni) {
        int n = n0 + wc * 64 + ni * 16 + q15;
        float v = acc[mi][ni][r] + biasv[ni]
                + LORA_SCALE * (xv.x * lbv4[ni].x + xv.y * lbv4[ni].y +
                                xv.z * lbv4[ni].z + xv.w * lbv4[ni].w);
        if (p == 0) v *= 0.125f;   // fold 1/sqrt(HD) into Q (exact power of 2)
        int h = n >> 6, d = n & 63;
        qkv[p * 4194304 + ((b * 16 + h) * 2048 + s) * 64 + d] = f2bf(v);
      }
    }
  }
}

// ---------------- Kernel 4: causal flash attention ----------------
// Block = (q-tile of 64 rows, one bh). 4 waves x 16 q-rows. Swapped QK^T:
// S^T = mfma(K_rows, Q^T) so lane owns q = lane&15; softmax stats lane-local.
// PV via V^T in LDS with permuted key columns -> P packs directly into B-frag.
__global__ __launch_bounds__(256) void attn_kernel(
    const u16* __restrict__ qkv, const float* __restrict__ amask, float* __restrict__ out) {
  const int bh = blockIdx.y, b = bh >> 4, h = bh & 15;
  const int qt = (int)gridDim.x - 1 - (int)blockIdx.x;   // long blocks dispatch first
  const int tid = threadIdx.x, lane = tid & 63, w = tid >> 6;
  const int g = lane >> 4, ql = lane & 15;
  const u16* Qb = qkv + bh * 131072;
  const u16* Kb = qkv + 4194304 + bh * 131072;
  const u16* Vb = qkv + 8388608 + bh * 131072;
  __shared__ __align__(16) u16 Ks[32 * 64];     // chunk-XOR-swizzled rows
  __shared__ __align__(16) u16 Vlin[32 * 64];   // linear staging
  __shared__ __align__(16) u16 VT[64 * 40];     // V^T, key-permuted cols, stride 40
  __shared__ float maskS[32];
  const int qg = qt * 64 + w * 16 + ql;
  const int qmax = qt * 64 + w * 16 + 15;
  bf16x8 qf[2];
  qf[0] = *(const bf16x8*)&Qb[qg * 64 + g * 8];
  qf[1] = *(const bf16x8*)&Qb[qg * 64 + 32 + g * 8];
  const f32x4 fzero = {0.f, 0.f, 0.f, 0.f};
  f32x4 acc[4];
#pragma unroll
  for (int dt = 0; dt < 4; ++dt) acc[dt] = fzero;
  float m_run = -1e30f, l_run = 0.f;
  const int kv_end = qt * 64 + 64;

  for (int kb = 0; kb < kv_end; kb += 32) {
    // ---- phase 1: stage K (swizzled), V (linear), mask ----
    {
      int key = tid >> 3, j = tid & 7;
      uint4 kd = *(const uint4*)&Kb[(kb + key) * 64 + j * 8];
      *(uint4*)&Ks[key * 64 + ((j ^ (key & 7)) * 8)] = kd;
      uint4 vd = *(const uint4*)&Vb[(kb + key) * 64 + j * 8];
      *(uint4*)&Vlin[key * 64 + j * 8] = vd;
      if (tid < 32) maskS[tid] = amask[b * 2048 + kb + tid];
    }
    __syncthreads();
    // ---- phase 3: QK^T MFMAs + mask reg-load; V transpose ----
    f32x4 st0 = fzero, st1 = fzero;
    float mk[8];
    if (kb <= qmax) {
#pragma unroll
      for (int ks = 0; ks < 2; ++ks) {
        bf16x8 kf0 = *(const bf16x8*)&Ks[ql * 64 + (((ks * 4 + g) ^ (ql & 7)) * 8)];
        st0 = __builtin_amdgcn_mfma_f32_16x16x32_bf16(kf0, qf[ks], st0, 0, 0, 0);
        bf16x8 kf1 = *(const bf16x8*)&Ks[(16 + ql) * 64 + (((ks * 4 + g) ^ (ql & 7)) * 8)];
        st1 = __builtin_amdgcn_mfma_f32_16x16x32_bf16(kf1, qf[ks], st1, 0, 0, 0);
      }
#pragma unroll
      for (int ss = 0; ss < 2; ++ss)
#pragma unroll
        for (int r = 0; r < 4; ++r) mk[ss * 4 + r] = maskS[ss * 16 + g * 4 + r];
    }
    {
      int d = lane;
      u16 tv[8];
#pragma unroll
      for (int jj = 0; jj < 8; ++jj) tv[jj] = Vlin[(w * 8 + jj) * 64 + d];
      int c0 = (w & 1) * 16 + (w >> 1) * 4;   // permuted column runs
      *(ushort4*)&VT[d * 40 + c0]     = make_ushort4(tv[0], tv[1], tv[2], tv[3]);
      *(ushort4*)&VT[d * 40 + c0 + 8] = make_ushort4(tv[4], tv[5], tv[6], tv[7]);
    }
    __syncthreads();
    // ---- phase 5: online softmax + PV ----
    if (kb <= qmax) {
      float sc[8];
      float mt = m_run;
#pragma unroll
      for (int ss = 0; ss < 2; ++ss)
#pragma unroll
        for (int r = 0; r < 4; ++r) {
          int kl = ss * 16 + g * 4 + r;
          float sv = (ss ? st1[r] : st0[r]) + mk[ss * 4 + r];
          if (kb + kl > qg) sv = -1e30f;   // causal
          sc[ss * 4 + r] = sv;
          mt = fmaxf(mt, sv);
        }
      mt = fmaxf(mt, __shfl_xor(mt, 16, 64));
      mt = fmaxf(mt, __shfl_xor(mt, 32, 64));
      float scale = __expf(m_run - mt);
      float pv[8]; float psum = 0.f;
#pragma unroll
      for (int i = 0; i < 8; ++i) { pv[i] = __expf(sc[i] - mt); psum += pv[i]; }
      psum += __shfl_xor(psum, 16, 64);
      psum += __shfl_xor(psum, 32, 64);
      l_run = l_run * scale + psum;
      m_run = mt;
#pragma unroll
      for (int dt = 0; dt < 4; ++dt) acc[dt] *= scale;
      union { bf16x8 v; u16 u[8]; } pf;
#pragma unroll
      for (int i = 0; i < 8; ++i) pf.u[i] = f2bf(pv[i]);
#pragma unroll
      for (int dt = 0; dt < 4; ++dt) {
        bf16x8 vf = *(const bf16x8*)&VT[(dt * 16 + ql) * 40 + g * 8];
        acc[dt] = __builtin_amdgcn_mfma_f32_16x16x32_bf16(vf, pf.v, acc[dt], 0, 0, 0);
      }
    }
  }

  float inv = 1.f / l_run;
#pragma unroll
  for (int dt = 0; dt < 4; ++dt) {
    f32x4 o = acc[dt] * inv;
    *(f32x4*)&out[(b * 2048 + qg) * 1024 + h * 64 + dt * 16 + g * 4] = o;
  }
}

// ---------------- launch ----------------
extern "C" void kernel_launch(void* const* d_in, const int* in_sizes, int n_in,
                              void* d_out, int out_size, void* d_ws, size_t ws_size,
                              hipStream_t stream) {
  const float* x  = (const float*)d_in[0];
  const float* am = (const float*)d_in[1];
  const float* Wq = (const float*)d_in[2];
  const float* bq = (const float*)d_in[3];
  const float* Aq = (const float*)d_in[4];
  const float* Bq = (const float*)d_in[5];
  const float* Wk = (const float*)d_in[6];
  const float* bk = (const float*)d_in[7];
  const float* Ak = (const float*)d_in[8];
  const float* Bk = (const float*)d_in[9];
  const float* Wv = (const float*)d_in[10];
  const float* bv = (const float*)d_in[11];
  const float* Av = (const float*)d_in[12];
  const float* Bv = (const float*)d_in[13];
  float* out = (float*)d_out;

  u16* xbf   = (u16*)d_ws;                     // 4194304 u16 = 8 MB
  u16* wbf   = xbf + 4194304;                  // 3145728 u16 = 6 MB
  float* xa  = (float*)(wbf + 3145728);        // 49152 f32 = 192 KB
  u16* qkv   = (u16*)(xa + 49152);             // 12582912 u16 = 24 MB

  cvt_kernel<<<1792, 256, 0, stream>>>(x, Wq, Wk, Wv, xbf, wbf);
  xa_kernel<<<1024, 256, 0, stream>>>(x, Aq, Ak, Av, xa);
  qkv_gemm<<<dim3(8, 32, 3), 256, 0, stream>>>(xbf, wbf, bq, bk, bv, Bq, Bk, Bv, xa, qkv);
  attn_kernel<<<dim3(32, 32), 256, 0, stream>>>(qkv, am, out);
}

// Round 2
// 144.413 us; speedup vs baseline: 1.1950x; 1.1950x over previous
//
#include <hip/hip_runtime.h>
#include <stdint.h>

// Problem constants
#define B_ 2
#define S_ 2048
#define H_ 1024
#define NH_ 16
#define HD_ 64
#define M_ 4096            // B*S
#define LORA_SCALE 4.0f
#define LOG2E 1.44269504089f

typedef unsigned short u16;
typedef __bf16 bf16x8 __attribute__((ext_vector_type(8)));
typedef float  f32x4  __attribute__((ext_vector_type(4)));

__device__ inline u16 f2bf(float f) {
  union { float f; uint32_t u; } a; a.f = f;
  uint32_t r = a.u + 0x7FFFu + ((a.u >> 16) & 1u);
  return (u16)(r >> 16);
}

__device__ inline void gload_lds16(const void* g, void* l) {
  __builtin_amdgcn_global_load_lds((const __attribute__((address_space(1))) void*)g,
                                   (__attribute__((address_space(3))) void*)l, 16, 0, 0);
}

// ---------------- Kernel 1: f32 -> bf16 convert (x and Wq/Wk/Wv) ----------------
__global__ __launch_bounds__(256) void cvt_kernel(
    const float* __restrict__ x,
    const float* __restrict__ wq, const float* __restrict__ wk, const float* __restrict__ wv,
    u16* __restrict__ xbf, u16* __restrict__ wbf) {
  const int XN = M_ * H_;            // 4194304
  const int WN = H_ * H_;            // 1048576
  const int total = XN + 3 * WN;
  int idx = (blockIdx.x * 256 + threadIdx.x) * 4;
  for (; idx < total; idx += gridDim.x * 256 * 4) {
    const float* src; u16* dst; int off;
    if (idx < XN) { src = x; dst = xbf; off = idx; }
    else {
      int j = idx - XN; int p = j >> 20; off = j & (WN - 1);
      src = (p == 0) ? wq : (p == 1 ? wk : wv);
      dst = wbf + (p << 20);
    }
    float4 v = *(const float4*)(src + off);
    *(ushort4*)(dst + off) = make_ushort4(f2bf(v.x), f2bf(v.y), f2bf(v.z), f2bf(v.w));
  }
}

// ---------------- Kernel 2: LoRA down-proj xa[p][m][r] = x[m,:].A_p[r,:] (f32) ----------------
__global__ __launch_bounds__(256) void xa_kernel(
    const float* __restrict__ x,
    const float* __restrict__ Aq, const float* __restrict__ Ak, const float* __restrict__ Av,
    float* __restrict__ xa) {
  const int w = threadIdx.x >> 6, lane = threadIdx.x & 63;
  const int m = blockIdx.x * 4 + w;
  float xv[16];
#pragma unroll
  for (int j = 0; j < 16; ++j) xv[j] = x[m * 1024 + j * 64 + lane];
  const float* Ap[3] = {Aq, Ak, Av};
  float s[12];
#pragma unroll
  for (int p = 0; p < 3; ++p) {
#pragma unroll
    for (int r = 0; r < 4; ++r) {
      const float* Ar = Ap[p] + r * 1024;
      float acc = 0.f;
#pragma unroll
      for (int j = 0; j < 16; ++j) acc += xv[j] * Ar[j * 64 + lane];
      s[p * 4 + r] = acc;
    }
  }
#pragma unroll
  for (int i = 0; i < 12; ++i) {
    float v = s[i];
#pragma unroll
    for (int off = 32; off >= 1; off >>= 1) v += __shfl_xor(v, off, 64);
    s[i] = v;
  }
  if (lane == 0) {
#pragma unroll
    for (int p = 0; p < 3; ++p)
#pragma unroll
      for (int r = 0; r < 4; ++r)
        xa[(p * M_ + m) * 4 + r] = s[p * 4 + r];
  }
}

// ---------------- Kernel 3: fused QKV GEMM (bf16 MFMA) + bias + LoRA-up epilogue ----------------
// out[m,n] = sum_k x[m,k] W_p[n,k] + b_p[n] + 4.0 * sum_r xa[p][m][r] * LB_p[n][r]
// Q: [bh][s][d], scaled by 0.125*log2(e) (exp2-domain softmax).
// K: [bh][s][d'] with 16B-unit XOR swizzle d_unit ^= (s&7)  (bank-conflict-free ds_read in attn).
// V: [bh][d][s'] transposed, with P-fragment column permutation + 16B-unit XOR swizzle baked in.
__global__ __launch_bounds__(256) void qkv_gemm(
    const u16* __restrict__ xbf, const u16* __restrict__ wbf,
    const float* __restrict__ bq, const float* __restrict__ bk, const float* __restrict__ bv,
    const float* __restrict__ lbq, const float* __restrict__ lbk, const float* __restrict__ lbv,
    const float* __restrict__ xa, u16* __restrict__ qkv) {
  const int p  = blockIdx.z;
  const int n0 = blockIdx.x * 128;
  const int m0 = blockIdx.y * 128;
  const u16* Wp = wbf + (p << 20);
  const float* bias = (p == 0) ? bq : (p == 1 ? bk : bv);
  const float* LB   = (p == 0) ? lbq : (p == 1 ? lbk : lbv);
  __shared__ __align__(16) u16 As[128 * 32];
  __shared__ __align__(16) u16 Bs[128 * 32];
  const int tid = threadIdx.x, lane = tid & 63, w = tid >> 6;
  const int g = lane >> 4, q15 = lane & 15;
  const int wr = w >> 1, wc = w & 1;
  const f32x4 fzero = {0.f, 0.f, 0.f, 0.f};
  f32x4 acc[4][4];
#pragma unroll
  for (int mi = 0; mi < 4; ++mi)
#pragma unroll
    for (int ni = 0; ni < 4; ++ni) acc[mi][ni] = fzero;
  const int srow = lane >> 2, scol = (lane & 3) * 8;

  for (int k0 = 0; k0 < 1024; k0 += 32) {
#pragma unroll
    for (int j = 0; j < 2; ++j) {
      int c = w * 2 + j;
      int row = c * 16 + srow;
      gload_lds16(xbf + (m0 + row) * 1024 + k0 + scol, As + c * 512);
      gload_lds16(Wp  + (n0 + row) * 1024 + k0 + scol, Bs + c * 512);
    }
    __syncthreads();
    bf16x8 af[4], bfr[4];
#pragma unroll
    for (int mi = 0; mi < 4; ++mi)
      af[mi] = *(const bf16x8*)&As[(wr * 64 + mi * 16 + q15) * 32 + g * 8];
#pragma unroll
    for (int ni = 0; ni < 4; ++ni)
      bfr[ni] = *(const bf16x8*)&Bs[(wc * 64 + ni * 16 + q15) * 32 + g * 8];
#pragma unroll
    for (int mi = 0; mi < 4; ++mi)
#pragma unroll
      for (int ni = 0; ni < 4; ++ni)
        acc[mi][ni] = __builtin_amdgcn_mfma_f32_16x16x32_bf16(af[mi], bfr[ni], acc[mi][ni], 0, 0, 0);
    __syncthreads();
  }

  // epilogue
  float biasv[4]; f32x4 lbv4[4];
#pragma unroll
  for (int ni = 0; ni < 4; ++ni) {
    int n = n0 + wc * 64 + ni * 16 + q15;
    biasv[ni] = bias[n];
    lbv4[ni] = *(const f32x4*)&LB[n * 4];
  }
#pragma unroll
  for (int mi = 0; mi < 4; ++mi) {
#pragma unroll
    for (int r = 0; r < 4; ++r) {
      int m = m0 + wr * 64 + mi * 16 + g * 4 + r;
      f32x4 xv = *(const f32x4*)&xa[(p * M_ + m) * 4];
      int b = m >> 11, s = m & 2047;
#pragma unroll
      for (int ni = 0; ni < 4; ++ni) {
        int n = n0 + wc * 64 + ni * 16 + q15;
        float v = acc[mi][ni][r] + biasv[ni]
                + LORA_SCALE * (xv.x * lbv4[ni].x + xv.y * lbv4[ni].y +
                                xv.z * lbv4[ni].z + xv.w * lbv4[ni].w);
        int h = n >> 6, d = n & 63;
        size_t bhs = (size_t)(b * 16 + h) * 2048 + s;
        if (p == 0) {
          v *= 0.125f * LOG2E;                 // fold 1/sqrt(HD) and log2(e) into Q
          qkv[bhs * 64 + d] = f2bf(v);
        } else if (p == 1) {
          int pos = (((d >> 3) ^ (s & 7)) << 3) | (d & 7);
          qkv[4194304 + bhs * 64 + pos] = f2bf(v);
        } else {
          int sr = s & 31;
          int c = (sr & 3) | (((sr >> 4) & 1) << 2) | (((sr >> 2) & 3) << 3);  // P-frag col perm
          int sp = (s & 32) | c;
          int spp = (((sp >> 3) ^ (d & 7)) << 3) | (sp & 7);                   // 16B-unit XOR swz
          qkv[8388608 + ((size_t)(b * 16 + h) * 64 + d) * 2048 + (s & ~63) + spp] = f2bf(v);
        }
      }
    }
  }
}

// ---------------- Kernel 4: causal flash attention (2-phase pipelined) ----------------
// Block = 128 q-rows x one bh, 4 waves x 32 q-rows each. KVBLK=64, double-buffered
// global_load_lds staging (pre-swizzled layouts -> conflict-free ds_read_b128).
// Swapped QK^T (lane owns q=lane&15); P packs into PV B-frag with zero cross-lane
// (V columns pre-permuted). One __syncthreads (vmcnt0+barrier) per 64-key tile.
__global__ __launch_bounds__(256, 2) void attn_kernel(
    const u16* __restrict__ qkv, const float* __restrict__ amask, float* __restrict__ out) {
  const int bid = blockIdx.x;
  const int bh = (bid & 7) * 4 + ((bid >> 3) & 3);   // 4 bh per XCD -> K/V L2-resident
  const int qt = 15 - ((bid >> 5) & 15);             // long blocks first
  const int b = bh >> 4, h = bh & 15;
  const int tid = threadIdx.x, lane = tid & 63, w = tid >> 6;
  const int g = lane >> 4, ql = lane & 15;
  const u16* Qb = qkv + (size_t)bh * 131072;
  const u16* Kb = qkv + 4194304 + (size_t)bh * 131072;
  const u16* Vb = qkv + 8388608 + (size_t)bh * 131072;   // [64][2048] transposed
  __shared__ __align__(16) u16 Ks[2][64][64];
  __shared__ __align__(16) u16 Vs[2][64][64];
  __shared__ float Ms[2][64];
  const int qw = qt * 128 + w * 32;

  bf16x8 qf[2][2];
#pragma unroll
  for (int qi = 0; qi < 2; ++qi)
#pragma unroll
    for (int ks = 0; ks < 2; ++ks)
      qf[qi][ks] = *(const bf16x8*)&Qb[(size_t)(qw + qi * 16 + ql) * 64 + ks * 32 + g * 8];

  const f32x4 fzero = {0.f, 0.f, 0.f, 0.f};
  f32x4 acc[2][4];
#pragma unroll
  for (int qi = 0; qi < 2; ++qi)
#pragma unroll
    for (int dt = 0; dt < 4; ++dt) acc[qi][dt] = fzero;
  float mrun[2] = {-1e30f, -1e30f}, lrun[2] = {0.f, 0.f};
  const int nt = 2 * (qt + 1);

  auto STAGE = [&](int nb, int kb) {
#pragma unroll
    for (int j = 0; j < 2; ++j) {
      int rl = w * 16 + j * 8 + (lane >> 3);
      gload_lds16(Kb + (size_t)(kb + rl) * 64 + (lane & 7) * 8, &Ks[nb][w * 16 + j * 8][0]);
      gload_lds16(Vb + (size_t)rl * 2048 + kb + (lane & 7) * 8, &Vs[nb][w * 16 + j * 8][0]);
    }
    if (tid < 64) Ms[nb][tid] = amask[b * 2048 + kb + tid] * LOG2E;
  };

  STAGE(0, 0);
  __syncthreads();

  for (int t = 0; t < nt; ++t) {
    const int kb = t * 64;
    if (t + 1 < nt) STAGE((t + 1) & 1, kb + 64);
    const int cb = t & 1;
    if (kb <= qw + 31) {
      // ---- QK^T: S^T tiles, lane owns q=ql, keys k16*16 + g*4 + r ----
      f32x4 st[2][4];
#pragma unroll
      for (int qi = 0; qi < 2; ++qi)
#pragma unroll
        for (int k16 = 0; k16 < 4; ++k16) st[qi][k16] = fzero;
#pragma unroll
      for (int k16 = 0; k16 < 4; ++k16) {
        bf16x8 kf0 = *(const bf16x8*)&Ks[cb][k16 * 16 + ql][(g ^ (ql & 7)) * 8];
        bf16x8 kf1 = *(const bf16x8*)&Ks[cb][k16 * 16 + ql][((4 + g) ^ (ql & 7)) * 8];
        st[0][k16] = __builtin_amdgcn_mfma_f32_16x16x32_bf16(kf0, qf[0][0], st[0][k16], 0, 0, 0);
        st[0][k16] = __builtin_amdgcn_mfma_f32_16x16x32_bf16(kf1, qf[0][1], st[0][k16], 0, 0, 0);
        st[1][k16] = __builtin_amdgcn_mfma_f32_16x16x32_bf16(kf0, qf[1][0], st[1][k16], 0, 0, 0);
        st[1][k16] = __builtin_amdgcn_mfma_f32_16x16x32_bf16(kf1, qf[1][1], st[1][k16], 0, 0, 0);
      }
      f32x4 mk[4];
#pragma unroll
      for (int k16 = 0; k16 < 4; ++k16) mk[k16] = *(const f32x4*)&Ms[cb][k16 * 16 + g * 4];
      // ---- online softmax (exp2 domain), P packs directly (V cols pre-permuted) ----
      bf16x8 pfv[2][2];
#pragma unroll
      for (int qi = 0; qi < 2; ++qi) {
        const int q = qw + qi * 16 + ql;
        const bool needm = (kb + 63 > qw + qi * 16);   // wave-uniform: diagonal tile?
        float sc[16], mt = mrun[qi];
#pragma unroll
        for (int k16 = 0; k16 < 4; ++k16)
#pragma unroll
          for (int r = 0; r < 4; ++r) {
            float sv = st[qi][k16][r] + mk[k16][r];
            if (needm) { int key = kb + k16 * 16 + g * 4 + r; sv = (key > q) ? -1e30f : sv; }
            sc[k16 * 4 + r] = sv;
            mt = fmaxf(mt, sv);
          }
        mt = fmaxf(mt, __shfl_xor(mt, 16, 64));
        mt = fmaxf(mt, __shfl_xor(mt, 32, 64));
        const float scale = exp2f(mrun[qi] - mt);
        float pv[16], ps = 0.f;
#pragma unroll
        for (int i = 0; i < 16; ++i) { pv[i] = exp2f(sc[i] - mt); ps += pv[i]; }
        ps += __shfl_xor(ps, 16, 64);
        ps += __shfl_xor(ps, 32, 64);
        lrun[qi] = lrun[qi] * scale + ps;
        mrun[qi] = mt;
#pragma unroll
        for (int dt = 0; dt < 4; ++dt) acc[qi][dt] *= scale;
#pragma unroll
        for (int ksub = 0; ksub < 2; ++ksub)
#pragma unroll
          for (int j = 0; j < 4; ++j) {
            pfv[qi][ksub][j]     = (__bf16)pv[ksub * 8 + j];
            pfv[qi][ksub][4 + j] = (__bf16)pv[ksub * 8 + 4 + j];
          }
      }
      // ---- PV: acc^T[d][q] += V^T P ----
#pragma unroll
      for (int dt = 0; dt < 4; ++dt)
#pragma unroll
        for (int ksub = 0; ksub < 2; ++ksub) {
          bf16x8 vf = *(const bf16x8*)&Vs[cb][dt * 16 + ql][((ksub * 4 + g) ^ (ql & 7)) * 8];
          acc[0][dt] = __builtin_amdgcn_mfma_f32_16x16x32_bf16(vf, pfv[0][ksub], acc[0][dt], 0, 0, 0);
          acc[1][dt] = __builtin_amdgcn_mfma_f32_16x16x32_bf16(vf, pfv[1][ksub], acc[1][dt], 0, 0, 0);
        }
    }
    __syncthreads();
  }

#pragma unroll
  for (int qi = 0; qi < 2; ++qi) {
    const float inv = 1.f / lrun[qi];
#pragma unroll
    for (int dt = 0; dt < 4; ++dt) {
      f32x4 o = acc[qi][dt] * inv;
      *(f32x4*)&out[((size_t)b * 2048 + qw + qi * 16 + ql) * 1024 + h * 64 + dt * 16 + g * 4] = o;
    }
  }
}

// ---------------- launch ----------------
extern "C" void kernel_launch(void* const* d_in, const int* in_sizes, int n_in,
                              void* d_out, int out_size, void* d_ws, size_t ws_size,
                              hipStream_t stream) {
  const float* x  = (const float*)d_in[0];
  const float* am = (const float*)d_in[1];
  const float* Wq = (const float*)d_in[2];
  const float* bq = (const float*)d_in[3];
  const float* Aq = (const float*)d_in[4];
  const float* Bq = (const float*)d_in[5];
  const float* Wk = (const float*)d_in[6];
  const float* bk = (const float*)d_in[7];
  const float* Ak = (const float*)d_in[8];
  const float* Bk = (const float*)d_in[9];
  const float* Wv = (const float*)d_in[10];
  const float* bv = (const float*)d_in[11];
  const float* Av = (const float*)d_in[12];
  const float* Bv = (const float*)d_in[13];
  float* out = (float*)d_out;

  u16* xbf   = (u16*)d_ws;                     // 4194304 u16 = 8 MB
  u16* wbf   = xbf + 4194304;                  // 3145728 u16 = 6 MB
  float* xa  = (float*)(wbf + 3145728);        // 49152 f32 = 192 KB
  u16* qkv   = (u16*)(xa + 49152);             // 12582912 u16 = 24 MB

  cvt_kernel<<<1792, 256, 0, stream>>>(x, Wq, Wk, Wv, xbf, wbf);
  xa_kernel<<<1024, 256, 0, stream>>>(x, Aq, Ak, Av, xa);
  qkv_gemm<<<dim3(8, 32, 3), 256, 0, stream>>>(xbf, wbf, bq, bk, bv, Bq, Bk, Bv, xa, qkv);
  attn_kernel<<<512, 256, 0, stream>>>(qkv, am, out);
}

// Round 3
// 135.780 us; speedup vs baseline: 1.2710x; 1.0636x over previous
//
#include <hip/hip_runtime.h>
#include <stdint.h>

// Problem constants
#define B_ 2
#define S_ 2048
#define H_ 1024
#define NH_ 16
#define HD_ 64
#define M_ 4096            // B*S
#define LORA_SCALE 4.0f
#define LOG2E 1.44269504089f

typedef unsigned short u16;
typedef __bf16 bf16x8 __attribute__((ext_vector_type(8)));
typedef float  f32x4  __attribute__((ext_vector_type(4)));

__device__ inline u16 f2bf(float f) {
  union { float f; uint32_t u; } a; a.f = f;
  uint32_t r = a.u + 0x7FFFu + ((a.u >> 16) & 1u);
  return (u16)(r >> 16);
}

__device__ inline void gload_lds16(const void* g, void* l) {
  __builtin_amdgcn_global_load_lds((const __attribute__((address_space(1))) void*)g,
                                   (__attribute__((address_space(3))) void*)l, 16, 0, 0);
}

// ---------------- Kernel 1: f32 -> bf16 convert (x and Wq/Wk/Wv) ----------------
__global__ __launch_bounds__(256) void cvt_kernel(
    const float* __restrict__ x,
    const float* __restrict__ wq, const float* __restrict__ wk, const float* __restrict__ wv,
    u16* __restrict__ xbf, u16* __restrict__ wbf) {
  const int XN = M_ * H_;            // 4194304
  const int WN = H_ * H_;            // 1048576
  const int total = XN + 3 * WN;
  int idx = (blockIdx.x * 256 + threadIdx.x) * 4;
  for (; idx < total; idx += gridDim.x * 256 * 4) {
    const float* src; u16* dst; int off;
    if (idx < XN) { src = x; dst = xbf; off = idx; }
    else {
      int j = idx - XN; int p = j >> 20; off = j & (WN - 1);
      src = (p == 0) ? wq : (p == 1 ? wk : wv);
      dst = wbf + (p << 20);
    }
    float4 v = *(const float4*)(src + off);
    *(ushort4*)(dst + off) = make_ushort4(f2bf(v.x), f2bf(v.y), f2bf(v.z), f2bf(v.w));
  }
}

// ---------------- Kernel 2: LoRA down-proj xa[p][m][r] = x[m,:].A_p[r,:] (f32) ----------------
__global__ __launch_bounds__(256) void xa_kernel(
    const float* __restrict__ x,
    const float* __restrict__ Aq, const float* __restrict__ Ak, const float* __restrict__ Av,
    float* __restrict__ xa) {
  const int w = threadIdx.x >> 6, lane = threadIdx.x & 63;
  const int m = blockIdx.x * 4 + w;
  float xv[16];
#pragma unroll
  for (int j = 0; j < 16; ++j) xv[j] = x[m * 1024 + j * 64 + lane];
  const float* Ap[3] = {Aq, Ak, Av};
  float s[12];
#pragma unroll
  for (int p = 0; p < 3; ++p) {
#pragma unroll
    for (int r = 0; r < 4; ++r) {
      const float* Ar = Ap[p] + r * 1024;
      float acc = 0.f;
#pragma unroll
      for (int j = 0; j < 16; ++j) acc += xv[j] * Ar[j * 64 + lane];
      s[p * 4 + r] = acc;
    }
  }
#pragma unroll
  for (int i = 0; i < 12; ++i) {
    float v = s[i];
#pragma unroll
    for (int off = 32; off >= 1; off >>= 1) v += __shfl_xor(v, off, 64);
    s[i] = v;
  }
  if (lane == 0) {
#pragma unroll
    for (int p = 0; p < 3; ++p)
#pragma unroll
      for (int r = 0; r < 4; ++r)
        xa[(p * M_ + m) * 4 + r] = s[p * 4 + r];
  }
}

// ---------------- Kernel 3: fused QKV GEMM (bf16 MFMA) + bias + LoRA-up epilogue ----------------
// Double-buffered LDS, ONE __syncthreads per K-step (T3-minimum 2-phase):
// STAGE(t+1) issued before compute(t), loads stay in flight across the MFMA cluster.
// LDS bank-conflict fix (rule #21 both-sides): global source unit pre-XOR'd with
// (row>>1)&3, LDS stays linear, fragment read applies the same XOR -> 2-way (free).
__global__ __launch_bounds__(256) void qkv_gemm(
    const u16* __restrict__ xbf, const u16* __restrict__ wbf,
    const float* __restrict__ bq, const float* __restrict__ bk, const float* __restrict__ bv,
    const float* __restrict__ lbq, const float* __restrict__ lbk, const float* __restrict__ lbv,
    const float* __restrict__ xa, u16* __restrict__ qkv) {
  const int p  = blockIdx.z;
  const int n0 = blockIdx.x * 128;
  const int m0 = blockIdx.y * 128;
  const u16* Wp = wbf + (p << 20);
  const float* bias = (p == 0) ? bq : (p == 1 ? bk : bv);
  const float* LB   = (p == 0) ? lbq : (p == 1 ? lbk : lbv);
  __shared__ __align__(16) u16 As[2][128 * 32];
  __shared__ __align__(16) u16 Bs[2][128 * 32];
  const int tid = threadIdx.x, lane = tid & 63, w = tid >> 6;
  const int g = lane >> 4, q15 = lane & 15;
  const int wr = w >> 1, wc = w & 1;
  const f32x4 fzero = {0.f, 0.f, 0.f, 0.f};
  f32x4 acc[4][4];
#pragma unroll
  for (int mi = 0; mi < 4; ++mi)
#pragma unroll
    for (int ni = 0; ni < 4; ++ni) acc[mi][ni] = fzero;
  const int srow = lane >> 2;

  auto STAGE = [&](int buf, int k0) {
#pragma unroll
    for (int j = 0; j < 2; ++j) {
      int c = w * 2 + j;
      int row = c * 16 + srow;
      int uu = (lane & 3) ^ ((row >> 1) & 3);     // pre-swizzled global 16B-unit
      gload_lds16(xbf + (size_t)(m0 + row) * 1024 + k0 + uu * 8, &As[buf][c * 512]);
      gload_lds16(Wp  + (size_t)(n0 + row) * 1024 + k0 + uu * 8, &Bs[buf][c * 512]);
    }
  };

  STAGE(0, 0);
  for (int t = 0; t < 32; ++t) {
    __syncthreads();                  // vmcnt(0): buf[t&1] staged; prev compute done
    if (t + 1 < 32) STAGE((t + 1) & 1, (t + 1) * 32);
    const int cb = t & 1;
    bf16x8 af[4], bfr[4];
#pragma unroll
    for (int mi = 0; mi < 4; ++mi) {
      int r = wr * 64 + mi * 16 + q15;
      af[mi] = *(const bf16x8*)&As[cb][r * 32 + ((g ^ ((r >> 1) & 3)) * 8)];
    }
#pragma unroll
    for (int ni = 0; ni < 4; ++ni) {
      int r = wc * 64 + ni * 16 + q15;
      bfr[ni] = *(const bf16x8*)&Bs[cb][r * 32 + ((g ^ ((r >> 1) & 3)) * 8)];
    }
#pragma unroll
    for (int mi = 0; mi < 4; ++mi)
#pragma unroll
      for (int ni = 0; ni < 4; ++ni)
        acc[mi][ni] = __builtin_amdgcn_mfma_f32_16x16x32_bf16(af[mi], bfr[ni], acc[mi][ni], 0, 0, 0);
  }

  // epilogue
  float biasv[4]; f32x4 lbv4[4];
#pragma unroll
  for (int ni = 0; ni < 4; ++ni) {
    int n = n0 + wc * 64 + ni * 16 + q15;
    biasv[ni] = bias[n];
    lbv4[ni] = *(const f32x4*)&LB[n * 4];
  }
#pragma unroll
  for (int mi = 0; mi < 4; ++mi) {
#pragma unroll
    for (int r = 0; r < 4; ++r) {
      int m = m0 + wr * 64 + mi * 16 + g * 4 + r;
      f32x4 xv = *(const f32x4*)&xa[(p * M_ + m) * 4];
      int b = m >> 11, s = m & 2047;
#pragma unroll
      for (int ni = 0; ni < 4; ++ni) {
        int n = n0 + wc * 64 + ni * 16 + q15;
        float v = acc[mi][ni][r] + biasv[ni]
                + LORA_SCALE * (xv.x * lbv4[ni].x + xv.y * lbv4[ni].y +
                                xv.z * lbv4[ni].z + xv.w * lbv4[ni].w);
        int h = n >> 6, d = n & 63;
        size_t bhs = (size_t)(b * 16 + h) * 2048 + s;
        if (p == 0) {
          v *= 0.125f * LOG2E;                 // fold 1/sqrt(HD) and log2(e) into Q
          qkv[bhs * 64 + d] = f2bf(v);
        } else if (p == 1) {
          int pos = (((d >> 3) ^ (s & 7)) << 3) | (d & 7);
          qkv[4194304 + bhs * 64 + pos] = f2bf(v);
        } else {
          int sr = s & 31;
          int c = (sr & 3) | (((sr >> 4) & 1) << 2) | (((sr >> 2) & 3) << 3);  // P-frag col perm
          int sp = (s & 32) | c;
          int spp = (((sp >> 3) ^ (d & 7)) << 3) | (sp & 7);                   // 16B-unit XOR swz
          qkv[8388608 + ((size_t)(b * 16 + h) * 64 + d) * 2048 + (s & ~63) + spp] = f2bf(v);
        }
      }
    }
  }
}

// ---------------- Kernel 4: causal flash attention (2-phase pipelined) ----------------
__global__ __launch_bounds__(256, 2) void attn_kernel(
    const u16* __restrict__ qkv, const float* __restrict__ amask, float* __restrict__ out) {
  const int bid = blockIdx.x;
  const int bh = (bid & 7) * 4 + ((bid >> 3) & 3);   // 4 bh per XCD -> K/V L2-resident
  const int qt = 15 - ((bid >> 5) & 15);             // long blocks first
  const int b = bh >> 4, h = bh & 15;
  const int tid = threadIdx.x, lane = tid & 63, w = tid >> 6;
  const int g = lane >> 4, ql = lane & 15;
  const u16* Qb = qkv + (size_t)bh * 131072;
  const u16* Kb = qkv + 4194304 + (size_t)bh * 131072;
  const u16* Vb = qkv + 8388608 + (size_t)bh * 131072;   // [64][2048] transposed
  __shared__ __align__(16) u16 Ks[2][64][64];
  __shared__ __align__(16) u16 Vs[2][64][64];
  __shared__ float Ms[2][64];
  const int qw = qt * 128 + w * 32;

  bf16x8 qf[2][2];
#pragma unroll
  for (int qi = 0; qi < 2; ++qi)
#pragma unroll
    for (int ks = 0; ks < 2; ++ks)
      qf[qi][ks] = *(const bf16x8*)&Qb[(size_t)(qw + qi * 16 + ql) * 64 + ks * 32 + g * 8];

  const f32x4 fzero = {0.f, 0.f, 0.f, 0.f};
  f32x4 acc[2][4];
#pragma unroll
  for (int qi = 0; qi < 2; ++qi)
#pragma unroll
    for (int dt = 0; dt < 4; ++dt) acc[qi][dt] = fzero;
  float mrun[2] = {-1e30f, -1e30f}, lrun[2] = {0.f, 0.f};
  const int nt = 2 * (qt + 1);

  auto STAGE = [&](int nb, int kb) {
#pragma unroll
    for (int j = 0; j < 2; ++j) {
      int rl = w * 16 + j * 8 + (lane >> 3);
      gload_lds16(Kb + (size_t)(kb + rl) * 64 + (lane & 7) * 8, &Ks[nb][w * 16 + j * 8][0]);
      gload_lds16(Vb + (size_t)rl * 2048 + kb + (lane & 7) * 8, &Vs[nb][w * 16 + j * 8][0]);
    }
    if (tid < 64) Ms[nb][tid] = amask[b * 2048 + kb + tid] * LOG2E;
  };

  STAGE(0, 0);
  __syncthreads();

  for (int t = 0; t < nt; ++t) {
    const int kb = t * 64;
    if (t + 1 < nt) STAGE((t + 1) & 1, kb + 64);
    const int cb = t & 1;
    if (kb <= qw + 31) {
      // ---- QK^T: S^T tiles, lane owns q=ql, keys k16*16 + g*4 + r ----
      f32x4 st[2][4];
#pragma unroll
      for (int qi = 0; qi < 2; ++qi)
#pragma unroll
        for (int k16 = 0; k16 < 4; ++k16) st[qi][k16] = fzero;
#pragma unroll
      for (int k16 = 0; k16 < 4; ++k16) {
        bf16x8 kf0 = *(const bf16x8*)&Ks[cb][k16 * 16 + ql][(g ^ (ql & 7)) * 8];
        bf16x8 kf1 = *(const bf16x8*)&Ks[cb][k16 * 16 + ql][((4 + g) ^ (ql & 7)) * 8];
        st[0][k16] = __builtin_amdgcn_mfma_f32_16x16x32_bf16(kf0, qf[0][0], st[0][k16], 0, 0, 0);
        st[0][k16] = __builtin_amdgcn_mfma_f32_16x16x32_bf16(kf1, qf[0][1], st[0][k16], 0, 0, 0);
        st[1][k16] = __builtin_amdgcn_mfma_f32_16x16x32_bf16(kf0, qf[1][0], st[1][k16], 0, 0, 0);
        st[1][k16] = __builtin_amdgcn_mfma_f32_16x16x32_bf16(kf1, qf[1][1], st[1][k16], 0, 0, 0);
      }
      f32x4 mk[4];
#pragma unroll
      for (int k16 = 0; k16 < 4; ++k16) mk[k16] = *(const f32x4*)&Ms[cb][k16 * 16 + g * 4];
      // ---- online softmax (exp2 domain), P packs directly (V cols pre-permuted) ----
      bf16x8 pfv[2][2];
#pragma unroll
      for (int qi = 0; qi < 2; ++qi) {
        const int q = qw + qi * 16 + ql;
        const bool needm = (kb + 63 > qw + qi * 16);   // wave-uniform: diagonal tile?
        float sc[16], mt = mrun[qi];
#pragma unroll
        for (int k16 = 0; k16 < 4; ++k16)
#pragma unroll
          for (int r = 0; r < 4; ++r) {
            float sv = st[qi][k16][r] + mk[k16][r];
            if (needm) { int key = kb + k16 * 16 + g * 4 + r; sv = (key > q) ? -1e30f : sv; }
            sc[k16 * 4 + r] = sv;
            mt = fmaxf(mt, sv);
          }
        mt = fmaxf(mt, __shfl_xor(mt, 16, 64));
        mt = fmaxf(mt, __shfl_xor(mt, 32, 64));
        const float scale = exp2f(mrun[qi] - mt);
        float pv[16], ps = 0.f;
#pragma unroll
        for (int i = 0; i < 16; ++i) { pv[i] = exp2f(sc[i] - mt); ps += pv[i]; }
        ps += __shfl_xor(ps, 16, 64);
        ps += __shfl_xor(ps, 32, 64);
        lrun[qi] = lrun[qi] * scale + ps;
        mrun[qi] = mt;
#pragma unroll
        for (int dt = 0; dt < 4; ++dt) acc[qi][dt] *= scale;
#pragma unroll
        for (int ksub = 0; ksub < 2; ++ksub)
#pragma unroll
          for (int j = 0; j < 4; ++j) {
            pfv[qi][ksub][j]     = (__bf16)pv[ksub * 8 + j];
            pfv[qi][ksub][4 + j] = (__bf16)pv[ksub * 8 + 4 + j];
          }
      }
      // ---- PV: acc^T[d][q] += V^T P ----
#pragma unroll
      for (int dt = 0; dt < 4; ++dt)
#pragma unroll
        for (int ksub = 0; ksub < 2; ++ksub) {
          bf16x8 vf = *(const bf16x8*)&Vs[cb][dt * 16 + ql][((ksub * 4 + g) ^ (ql & 7)) * 8];
          acc[0][dt] = __builtin_amdgcn_mfma_f32_16x16x32_bf16(vf, pfv[0][ksub], acc[0][dt], 0, 0, 0);
          acc[1][dt] = __builtin_amdgcn_mfma_f32_16x16x32_bf16(vf, pfv[1][ksub], acc[1][dt], 0, 0, 0);
        }
    }
    __syncthreads();
  }

#pragma unroll
  for (int qi = 0; qi < 2; ++qi) {
    const float inv = 1.f / lrun[qi];
#pragma unroll
    for (int dt = 0; dt < 4; ++dt) {
      f32x4 o = acc[qi][dt] * inv;
      *(f32x4*)&out[((size_t)b * 2048 + qw + qi * 16 + ql) * 1024 + h * 64 + dt * 16 + g * 4] = o;
    }
  }
}

// ---------------- launch ----------------
extern "C" void kernel_launch(void* const* d_in, const int* in_sizes, int n_in,
                              void* d_out, int out_size, void* d_ws, size_t ws_size,
                              hipStream_t stream) {
  const float* x  = (const float*)d_in[0];
  const float* am = (const float*)d_in[1];
  const float* Wq = (const float*)d_in[2];
  const float* bq = (const float*)d_in[3];
  const float* Aq = (const float*)d_in[4];
  const float* Bq = (const float*)d_in[5];
  const float* Wk = (const float*)d_in[6];
  const float* bk = (const float*)d_in[7];
  const float* Ak = (const float*)d_in[8];
  const float* Bk = (const float*)d_in[9];
  const float* Wv = (const float*)d_in[10];
  const float* bv = (const float*)d_in[11];
  const float* Av = (const float*)d_in[12];
  const float* Bv = (const float*)d_in[13];
  float* out = (float*)d_out;

  u16* xbf   = (u16*)d_ws;                     // 4194304 u16 = 8 MB
  u16* wbf   = xbf + 4194304;                  // 3145728 u16 = 6 MB
  float* xa  = (float*)(wbf + 3145728);        // 49152 f32 = 192 KB
  u16* qkv   = (u16*)(xa + 49152);             // 12582912 u16 = 24 MB

  cvt_kernel<<<1792, 256, 0, stream>>>(x, Wq, Wk, Wv, xbf, wbf);
  xa_kernel<<<1024, 256, 0, stream>>>(x, Aq, Ak, Av, xa);
  qkv_gemm<<<dim3(8, 32, 3), 256, 0, stream>>>(xbf, wbf, bq, bk, bv, Bq, Bk, Bv, xa, qkv);
  attn_kernel<<<512, 256, 0, stream>>>(qkv, am, out);
}

// Round 4
// 114.313 us; speedup vs baseline: 1.5097x; 1.1878x over previous
//
#include <hip/hip_runtime.h>
#include <stdint.h>

// Problem constants
#define B_ 2
#define S_ 2048
#define H_ 1024
#define NH_ 16
#define HD_ 64
#define M_ 4096            // B*S
#define LORA_SCALE 4.0f
#define LOG2E 1.44269504089f

typedef unsigned short u16;
typedef __bf16 bf16x8 __attribute__((ext_vector_type(8)));
typedef float  f32x4  __attribute__((ext_vector_type(4)));

#if __has_builtin(__builtin_amdgcn_exp2f)
#define EXP2(x) __builtin_amdgcn_exp2f(x)
#else
#define EXP2(x) exp2f(x)
#endif

__device__ inline u16 f2bf(float f) {
  union { float f; uint32_t u; } a; a.f = f;
  uint32_t r = a.u + 0x7FFFu + ((a.u >> 16) & 1u);
  return (u16)(r >> 16);
}

__device__ inline void gload_lds16(const void* g, void* l) {
  __builtin_amdgcn_global_load_lds((const __attribute__((address_space(1))) void*)g,
                                   (__attribute__((address_space(3))) void*)l, 16, 0, 0);
}

// ---------------- Kernel 1: f32 -> bf16 convert (x and Wq/Wk/Wv) ----------------
__global__ __launch_bounds__(256) void cvt_kernel(
    const float* __restrict__ x,
    const float* __restrict__ wq, const float* __restrict__ wk, const float* __restrict__ wv,
    u16* __restrict__ xbf, u16* __restrict__ wbf) {
  const int XN = M_ * H_;            // 4194304
  const int WN = H_ * H_;            // 1048576
  const int total = XN + 3 * WN;
  int idx = (blockIdx.x * 256 + threadIdx.x) * 4;
  for (; idx < total; idx += gridDim.x * 256 * 4) {
    const float* src; u16* dst; int off;
    if (idx < XN) { src = x; dst = xbf; off = idx; }
    else {
      int j = idx - XN; int p = j >> 20; off = j & (WN - 1);
      src = (p == 0) ? wq : (p == 1 ? wk : wv);
      dst = wbf + (p << 20);
    }
    float4 v = *(const float4*)(src + off);
    *(ushort4*)(dst + off) = make_ushort4(f2bf(v.x), f2bf(v.y), f2bf(v.z), f2bf(v.w));
  }
}

// ---------------- Kernel 2: LoRA down-proj xa[p][m][r] = x[m,:].A_p[r,:] (f32) ----------------
__global__ __launch_bounds__(256) void xa_kernel(
    const float* __restrict__ x,
    const float* __restrict__ Aq, const float* __restrict__ Ak, const float* __restrict__ Av,
    float* __restrict__ xa) {
  const int w = threadIdx.x >> 6, lane = threadIdx.x & 63;
  const int m = blockIdx.x * 4 + w;
  float xv[16];
#pragma unroll
  for (int j = 0; j < 16; ++j) xv[j] = x[m * 1024 + j * 64 + lane];
  const float* Ap[3] = {Aq, Ak, Av};
  float s[12];
#pragma unroll
  for (int p = 0; p < 3; ++p) {
#pragma unroll
    for (int r = 0; r < 4; ++r) {
      const float* Ar = Ap[p] + r * 1024;
      float acc = 0.f;
#pragma unroll
      for (int j = 0; j < 16; ++j) acc += xv[j] * Ar[j * 64 + lane];
      s[p * 4 + r] = acc;
    }
  }
#pragma unroll
  for (int i = 0; i < 12; ++i) {
    float v = s[i];
#pragma unroll
    for (int off = 32; off >= 1; off >>= 1) v += __shfl_xor(v, off, 64);
    s[i] = v;
  }
  if (lane == 0) {
#pragma unroll
    for (int p = 0; p < 3; ++p)
#pragma unroll
      for (int r = 0; r < 4; ++r)
        xa[(p * M_ + m) * 4 + r] = s[p * 4 + r];
  }
}

// ---------------- Kernel 3: fused QKV GEMM (bf16 MFMA) + bias + LoRA-up epilogue ----------------
__global__ __launch_bounds__(256) void qkv_gemm(
    const u16* __restrict__ xbf, const u16* __restrict__ wbf,
    const float* __restrict__ bq, const float* __restrict__ bk, const float* __restrict__ bv,
    const float* __restrict__ lbq, const float* __restrict__ lbk, const float* __restrict__ lbv,
    const float* __restrict__ xa, u16* __restrict__ qkv) {
  const int p  = blockIdx.z;
  const int n0 = blockIdx.x * 128;
  const int m0 = blockIdx.y * 128;
  const u16* Wp = wbf + (p << 20);
  const float* bias = (p == 0) ? bq : (p == 1 ? bk : bv);
  const float* LB   = (p == 0) ? lbq : (p == 1 ? lbk : lbv);
  __shared__ __align__(16) u16 As[2][128 * 32];
  __shared__ __align__(16) u16 Bs[2][128 * 32];
  const int tid = threadIdx.x, lane = tid & 63, w = tid >> 6;
  const int g = lane >> 4, q15 = lane & 15;
  const int wr = w >> 1, wc = w & 1;
  const f32x4 fzero = {0.f, 0.f, 0.f, 0.f};
  f32x4 acc[4][4];
#pragma unroll
  for (int mi = 0; mi < 4; ++mi)
#pragma unroll
    for (int ni = 0; ni < 4; ++ni) acc[mi][ni] = fzero;
  const int srow = lane >> 2;

  auto STAGE = [&](int buf, int k0) {
#pragma unroll
    for (int j = 0; j < 2; ++j) {
      int c = w * 2 + j;
      int row = c * 16 + srow;
      int uu = (lane & 3) ^ ((row >> 1) & 3);     // pre-swizzled global 16B-unit
      gload_lds16(xbf + (size_t)(m0 + row) * 1024 + k0 + uu * 8, &As[buf][c * 512]);
      gload_lds16(Wp  + (size_t)(n0 + row) * 1024 + k0 + uu * 8, &Bs[buf][c * 512]);
    }
  };

  STAGE(0, 0);
  for (int t = 0; t < 32; ++t) {
    __syncthreads();                  // vmcnt(0): buf[t&1] staged; prev compute done
    if (t + 1 < 32) STAGE((t + 1) & 1, (t + 1) * 32);
    const int cb = t & 1;
    bf16x8 af[4], bfr[4];
#pragma unroll
    for (int mi = 0; mi < 4; ++mi) {
      int r = wr * 64 + mi * 16 + q15;
      af[mi] = *(const bf16x8*)&As[cb][r * 32 + ((g ^ ((r >> 1) & 3)) * 8)];
    }
#pragma unroll
    for (int ni = 0; ni < 4; ++ni) {
      int r = wc * 64 + ni * 16 + q15;
      bfr[ni] = *(const bf16x8*)&Bs[cb][r * 32 + ((g ^ ((r >> 1) & 3)) * 8)];
    }
#pragma unroll
    for (int mi = 0; mi < 4; ++mi)
#pragma unroll
      for (int ni = 0; ni < 4; ++ni)
        acc[mi][ni] = __builtin_amdgcn_mfma_f32_16x16x32_bf16(af[mi], bfr[ni], acc[mi][ni], 0, 0, 0);
  }

  // epilogue
  float biasv[4]; f32x4 lbv4[4];
#pragma unroll
  for (int ni = 0; ni < 4; ++ni) {
    int n = n0 + wc * 64 + ni * 16 + q15;
    biasv[ni] = bias[n];
    lbv4[ni] = *(const f32x4*)&LB[n * 4];
  }
#pragma unroll
  for (int mi = 0; mi < 4; ++mi) {
#pragma unroll
    for (int r = 0; r < 4; ++r) {
      int m = m0 + wr * 64 + mi * 16 + g * 4 + r;
      f32x4 xv = *(const f32x4*)&xa[(p * M_ + m) * 4];
      int b = m >> 11, s = m & 2047;
#pragma unroll
      for (int ni = 0; ni < 4; ++ni) {
        int n = n0 + wc * 64 + ni * 16 + q15;
        float v = acc[mi][ni][r] + biasv[ni]
                + LORA_SCALE * (xv.x * lbv4[ni].x + xv.y * lbv4[ni].y +
                                xv.z * lbv4[ni].z + xv.w * lbv4[ni].w);
        int h = n >> 6, d = n & 63;
        size_t bhs = (size_t)(b * 16 + h) * 2048 + s;
        if (p == 0) {
          v *= 0.125f * LOG2E;                 // fold 1/sqrt(HD) and log2(e) into Q
          qkv[bhs * 64 + d] = f2bf(v);
        } else if (p == 1) {
          int pos = (((d >> 3) ^ (s & 7)) << 3) | (d & 7);
          qkv[4194304 + bhs * 64 + pos] = f2bf(v);
        } else {
          int sr = s & 31;
          int c = (sr & 3) | (((sr >> 4) & 1) << 2) | (((sr >> 2) & 3) << 3);  // P-frag col perm
          int sp = (s & 32) | c;
          int spp = (((sp >> 3) ^ (d & 7)) << 3) | (sp & 7);                   // 16B-unit XOR swz
          qkv[8388608 + ((size_t)(b * 16 + h) * 64 + d) * 2048 + (s & ~63) + spp] = f2bf(v);
        }
      }
    }
  }
}

// ---------------- Kernel 4: causal flash attention ----------------
// Block = 4 waves x 16 q-rows = 64-q tile; each block processes the PAIR
// (qt, 31-qt) sequentially -> exactly 33 key-tiles per block (uniform work,
// 512 blocks = steady 2/CU). Raw v_exp_f32, defer-max (THR=8, log2 domain),
// deferred l-reduce, setprio around MFMA clusters.
__global__ __launch_bounds__(256, 2) void attn_kernel(
    const u16* __restrict__ qkv, const float* __restrict__ amask, float* __restrict__ out) {
  const int bid = blockIdx.x;
  const int bh = (bid & 7) * 4 + ((bid >> 3) & 3);   // 4 bh per XCD -> K/V L2-resident
  const int pi = bid >> 5;                           // 0..15 pair index
  const int b = bh >> 4, h = bh & 15;
  const int tid = threadIdx.x, lane = tid & 63, w = tid >> 6;
  const int g = lane >> 4, ql = lane & 15;
  const u16* Qb = qkv + (size_t)bh * 131072;
  const u16* Kb = qkv + 4194304 + (size_t)bh * 131072;
  const u16* Vb = qkv + 8388608 + (size_t)bh * 131072;   // [64][2048] transposed
  __shared__ __align__(16) u16 Ks[2][64][64];
  __shared__ __align__(16) u16 Vs[2][64][64];
  __shared__ float Ms[2][64];
  const f32x4 fzero = {0.f, 0.f, 0.f, 0.f};

  auto STAGE = [&](int nb, int kb) {
#pragma unroll
    for (int j = 0; j < 2; ++j) {
      int rl = w * 16 + j * 8 + (lane >> 3);
      gload_lds16(Kb + (size_t)(kb + rl) * 64 + (lane & 7) * 8, &Ks[nb][w * 16 + j * 8][0]);
      gload_lds16(Vb + (size_t)rl * 2048 + kb + (lane & 7) * 8, &Vs[nb][w * 16 + j * 8][0]);
    }
    if (tid < 64) Ms[nb][tid] = amask[b * 2048 + kb + tid] * LOG2E;
  };

#pragma unroll 1
  for (int ph = 0; ph < 2; ++ph) {
    const int qt = ph ? (31 - pi) : pi;
    const int qw = qt * 64 + w * 16;
    const int q  = qw + ql;
    bf16x8 qf[2];
#pragma unroll
    for (int ks = 0; ks < 2; ++ks)
      qf[ks] = *(const bf16x8*)&Qb[(size_t)q * 64 + ks * 32 + g * 8];
    f32x4 acc[4];
#pragma unroll
    for (int dt = 0; dt < 4; ++dt) acc[dt] = fzero;
    float mrun = -1e30f, lrun = 0.f;
    const int nt = qt + 1;

    STAGE(0, 0);
    __syncthreads();

#pragma unroll 1
    for (int t = 0; t < nt; ++t) {
      const int kb = t * 64;
      if (t + 1 < nt) STAGE((t + 1) & 1, kb + 64);
      const int cb = t & 1;
      // ---- QK^T: S^T, lane owns q=ql; keys k16*16 + g*4 + r ----
      f32x4 st[4];
#pragma unroll
      for (int k16 = 0; k16 < 4; ++k16) st[k16] = fzero;
      __builtin_amdgcn_s_setprio(1);
#pragma unroll
      for (int k16 = 0; k16 < 4; ++k16) {
        bf16x8 kf0 = *(const bf16x8*)&Ks[cb][k16 * 16 + ql][(g ^ (ql & 7)) * 8];
        bf16x8 kf1 = *(const bf16x8*)&Ks[cb][k16 * 16 + ql][((4 + g) ^ (ql & 7)) * 8];
        st[k16] = __builtin_amdgcn_mfma_f32_16x16x32_bf16(kf0, qf[0], st[k16], 0, 0, 0);
        st[k16] = __builtin_amdgcn_mfma_f32_16x16x32_bf16(kf1, qf[1], st[k16], 0, 0, 0);
      }
      __builtin_amdgcn_s_setprio(0);
      f32x4 mk[4];
#pragma unroll
      for (int k16 = 0; k16 < 4; ++k16) mk[k16] = *(const f32x4*)&Ms[cb][k16 * 16 + g * 4];
      // ---- online softmax (log2 domain, defer-max THR=8) ----
      const bool needm = (t == nt - 1);            // diagonal tile only (wave-uniform)
      float sc[16], pmax = -1e30f;
#pragma unroll
      for (int k16 = 0; k16 < 4; ++k16)
#pragma unroll
        for (int r = 0; r < 4; ++r) {
          float sv = st[k16][r] + mk[k16][r];
          if (needm) { int key = kb + k16 * 16 + g * 4 + r; sv = (key > q) ? -1e30f : sv; }
          sc[k16 * 4 + r] = sv;
          pmax = fmaxf(pmax, sv);
        }
      if (!__all(pmax <= mrun + 8.f)) {            // rescale only when max grows
        float pm = fmaxf(pmax, __shfl_xor(pmax, 16, 64));
        pm = fmaxf(pm, __shfl_xor(pm, 32, 64));
        const float mt = fmaxf(mrun, pm);
        const float scale = EXP2(mrun - mt);
        lrun *= scale;
#pragma unroll
        for (int dt = 0; dt < 4; ++dt) acc[dt] *= scale;
        mrun = mt;
      }
      float pv[16], ps = 0.f;
#pragma unroll
      for (int i = 0; i < 16; ++i) { pv[i] = EXP2(sc[i] - mrun); ps += pv[i]; }
      lrun += ps;                                  // per-lane partial; reduced in epilogue
      bf16x8 pfv[2];
#pragma unroll
      for (int ksub = 0; ksub < 2; ++ksub)
#pragma unroll
        for (int j = 0; j < 4; ++j) {
          pfv[ksub][j]     = (__bf16)pv[ksub * 8 + j];
          pfv[ksub][4 + j] = (__bf16)pv[ksub * 8 + 4 + j];
        }
      // ---- PV: acc^T[d][q] += V^T P ----
      __builtin_amdgcn_s_setprio(1);
#pragma unroll
      for (int dt = 0; dt < 4; ++dt)
#pragma unroll
        for (int ksub = 0; ksub < 2; ++ksub) {
          bf16x8 vf = *(const bf16x8*)&Vs[cb][dt * 16 + ql][((ksub * 4 + g) ^ (ql & 7)) * 8];
          acc[dt] = __builtin_amdgcn_mfma_f32_16x16x32_bf16(vf, pfv[ksub], acc[dt], 0, 0, 0);
        }
      __builtin_amdgcn_s_setprio(0);
      __syncthreads();
    }

    float lsum = lrun;
    lsum += __shfl_xor(lsum, 16, 64);
    lsum += __shfl_xor(lsum, 32, 64);
    const float inv = 1.f / lsum;
#pragma unroll
    for (int dt = 0; dt < 4; ++dt) {
      f32x4 o = acc[dt] * inv;
      *(f32x4*)&out[((size_t)b * 2048 + q) * 1024 + h * 64 + dt * 16 + g * 4] = o;
    }
  }
}

// ---------------- launch ----------------
extern "C" void kernel_launch(void* const* d_in, const int* in_sizes, int n_in,
                              void* d_out, int out_size, void* d_ws, size_t ws_size,
                              hipStream_t stream) {
  const float* x  = (const float*)d_in[0];
  const float* am = (const float*)d_in[1];
  const float* Wq = (const float*)d_in[2];
  const float* bq = (const float*)d_in[3];
  const float* Aq = (const float*)d_in[4];
  const float* Bq = (const float*)d_in[5];
  const float* Wk = (const float*)d_in[6];
  const float* bk = (const float*)d_in[7];
  const float* Ak = (const float*)d_in[8];
  const float* Bk = (const float*)d_in[9];
  const float* Wv = (const float*)d_in[10];
  const float* bv = (const float*)d_in[11];
  const float* Av = (const float*)d_in[12];
  const float* Bv = (const float*)d_in[13];
  float* out = (float*)d_out;

  u16* xbf   = (u16*)d_ws;                     // 4194304 u16 = 8 MB
  u16* wbf   = xbf + 4194304;                  // 3145728 u16 = 6 MB
  float* xa  = (float*)(wbf + 3145728);        // 49152 f32 = 192 KB
  u16* qkv   = (u16*)(xa + 49152);             // 12582912 u16 = 24 MB

  cvt_kernel<<<1792, 256, 0, stream>>>(x, Wq, Wk, Wv, xbf, wbf);
  xa_kernel<<<1024, 256, 0, stream>>>(x, Aq, Ak, Av, xa);
  qkv_gemm<<<dim3(8, 32, 3), 256, 0, stream>>>(xbf, wbf, bq, bk, bv, Bq, Bk, Bv, xa, qkv);
  attn_kernel<<<512, 256, 0, stream>>>(qkv, am, out);
}

// Round 5
// 89.545 us; speedup vs baseline: 1.9272x; 1.2766x over previous
//
#include <hip/hip_runtime.h>
#include <stdint.h>

// Problem constants
#define B_ 2
#define S_ 2048
#define H_ 1024
#define NH_ 16
#define HD_ 64
#define M_ 4096            // B*S
#define LOG2E 1.44269504089f

typedef unsigned short u16;
typedef __bf16 bf16x8 __attribute__((ext_vector_type(8)));
typedef float  f32x4  __attribute__((ext_vector_type(4)));

#if __has_builtin(__builtin_amdgcn_exp2f)
#define EXP2(x) __builtin_amdgcn_exp2f(x)
#else
#define EXP2(x) exp2f(x)
#endif

#define WAITV4() asm volatile("s_waitcnt vmcnt(4)" ::: "memory")
#define WAITV0() asm volatile("s_waitcnt vmcnt(0)" ::: "memory")
#define LGKM0()  asm volatile("s_waitcnt lgkmcnt(0)" ::: "memory")
#define SCHED0() __builtin_amdgcn_sched_barrier(0)

__device__ inline u16 f2bf(float f) {
  union { float f; uint32_t u; } a; a.f = f;
  uint32_t r = a.u + 0x7FFFu + ((a.u >> 16) & 1u);
  return (u16)(r >> 16);
}

__device__ inline void gload_lds16(const void* g, void* l) {
  __builtin_amdgcn_global_load_lds((const __attribute__((address_space(1))) void*)g,
                                   (__attribute__((address_space(3))) void*)l, 16, 0, 0);
}

// ---------------- Kernel 1: f32 -> bf16 convert; W' = W + 4*LB*A folded (exact) ----------------
__global__ __launch_bounds__(256) void cvt_kernel(
    const float* __restrict__ x,
    const float* __restrict__ wq, const float* __restrict__ wk, const float* __restrict__ wv,
    const float* __restrict__ Aq, const float* __restrict__ Ak, const float* __restrict__ Av,
    const float* __restrict__ LBq, const float* __restrict__ LBk, const float* __restrict__ LBv,
    u16* __restrict__ xbf, u16* __restrict__ wbf) {
  const int XN = M_ * H_;            // 4194304
  const int WN = H_ * H_;            // 1048576
  int idx = (blockIdx.x * 256 + threadIdx.x) * 4;   // grid sized exactly: (XN+3WN)/4/256 blocks
  if (idx < XN) {
    float4 v = *(const float4*)(x + idx);
    *(ushort4*)(xbf + idx) = make_ushort4(f2bf(v.x), f2bf(v.y), f2bf(v.z), f2bf(v.w));
  } else {
    int j = idx - XN; int p = j >> 20; int off = j & (WN - 1);
    const float* W  = (p == 0) ? wq : (p == 1 ? wk : wv);
    const float* A  = (p == 0) ? Aq : (p == 1 ? Ak : Av);
    const float* LB = (p == 0) ? LBq : (p == 1 ? LBk : LBv);
    int n = off >> 10, k = off & 1023;
    float4 v  = *(const float4*)(W + off);
    f32x4 lb  = *(const f32x4*)&LB[n * 4];
    float4 a0 = *(const float4*)(A + k);
    float4 a1 = *(const float4*)(A + 1024 + k);
    float4 a2 = *(const float4*)(A + 2048 + k);
    float4 a3 = *(const float4*)(A + 3072 + k);
    v.x += 4.f * (lb.x * a0.x + lb.y * a1.x + lb.z * a2.x + lb.w * a3.x);
    v.y += 4.f * (lb.x * a0.y + lb.y * a1.y + lb.z * a2.y + lb.w * a3.y);
    v.z += 4.f * (lb.x * a0.z + lb.y * a1.z + lb.z * a2.z + lb.w * a3.z);
    v.w += 4.f * (lb.x * a0.w + lb.y * a1.w + lb.z * a2.w + lb.w * a3.w);
    *(ushort4*)(wbf + (p << 20) + off) = make_ushort4(f2bf(v.x), f2bf(v.y), f2bf(v.z), f2bf(v.w));
  }
}

// ---------------- Kernel 2: fused QKV GEMM, 3-buffer counted-vmcnt pipeline ----------------
// out[m,n] = sum_k x[m,k] W'_p[n,k] + b_p[n].  P templated (blockIdx.z switch):
// P in {0,1}: swapped MFMA operands -> acc reg index runs along n (d) -> ushort4 stores.
// P == 2   : normal order -> reg index runs along s -> ushort4 stores via V col-perm.
template<int P>
__device__ __forceinline__ void gemm_body(
    const u16* __restrict__ xbf, const u16* __restrict__ wbf,
    const float* __restrict__ bias, u16* __restrict__ qkv,
    u16* __restrict__ As, u16* __restrict__ Bs) {
  const int n0 = blockIdx.x * 128;
  const int m0 = blockIdx.y * 128;
  const u16* Wp = wbf + (P << 20);
  const int tid = threadIdx.x, lane = tid & 63, w = tid >> 6;
  const int g = lane >> 4, q15 = lane & 15;
  const int wr = w >> 1, wc = w & 1;
  const f32x4 fzero = {0.f, 0.f, 0.f, 0.f};
  f32x4 acc[4][4];
#pragma unroll
  for (int mi = 0; mi < 4; ++mi)
#pragma unroll
    for (int ni = 0; ni < 4; ++ni) acc[mi][ni] = fzero;
  const int srow = lane >> 2;

  auto STAGE = [&](int buf, int k0) {
#pragma unroll
    for (int j = 0; j < 2; ++j) {
      int c = w * 2 + j;
      int row = c * 16 + srow;
      int uu = (lane & 3) ^ ((row >> 1) & 3);     // pre-swizzled global 16B-unit
      gload_lds16(xbf + (size_t)(m0 + row) * 1024 + k0 + uu * 8, As + buf * 4096 + c * 512);
      gload_lds16(Wp  + (size_t)(n0 + row) * 1024 + k0 + uu * 8, Bs + buf * 4096 + c * 512);
    }
  };

  STAGE(0, 0);
  STAGE(1, 32);
  int c0 = 0, c1 = 1, c2 = 2;
#pragma unroll 1
  for (int t = 0; t < 32; ++t) {
    if (t < 31) WAITV4(); else WAITV0();   // own stage(t) landed; stage(t+1) stays in flight
    SCHED0();
    __builtin_amdgcn_s_barrier();          // all waves' stage(t) landed; buf[c2] reads done
    if (t + 2 < 32) STAGE(c2, (t + 2) * 32);
    const u16* Ab = As + c0 * 4096;
    const u16* Bb = Bs + c0 * 4096;
    bf16x8 af[4], bfr[4];
#pragma unroll
    for (int mi = 0; mi < 4; ++mi) {
      int r = wr * 64 + mi * 16 + q15;
      af[mi] = *(const bf16x8*)&Ab[r * 32 + ((g ^ ((r >> 1) & 3)) * 8)];
    }
#pragma unroll
    for (int ni = 0; ni < 4; ++ni) {
      int r = wc * 64 + ni * 16 + q15;
      bfr[ni] = *(const bf16x8*)&Bb[r * 32 + ((g ^ ((r >> 1) & 3)) * 8)];
    }
    __builtin_amdgcn_s_setprio(1);
#pragma unroll
    for (int mi = 0; mi < 4; ++mi)
#pragma unroll
      for (int ni = 0; ni < 4; ++ni) {
        if (P == 2)
          acc[mi][ni] = __builtin_amdgcn_mfma_f32_16x16x32_bf16(af[mi], bfr[ni], acc[mi][ni], 0, 0, 0);
        else
          acc[mi][ni] = __builtin_amdgcn_mfma_f32_16x16x32_bf16(bfr[ni], af[mi], acc[mi][ni], 0, 0, 0);
      }
    __builtin_amdgcn_s_setprio(0);
    int tmp = c0; c0 = c1; c1 = c2; c2 = tmp;
  }

  // ---- epilogue: bias + vectorized ushort4 stores ----
  if (P != 2) {
    // acc[mi][ni]: col=q15 -> m-sub, row g*4+r -> n-sub
#pragma unroll
    for (int ni = 0; ni < 4; ++ni) {
      int nb = n0 + wc * 64 + ni * 16 + g * 4;       // 4-aligned
      f32x4 bi = *(const f32x4*)&bias[nb];
      int h = nb >> 6, dbase = nb & 63;
#pragma unroll
      for (int mi = 0; mi < 4; ++mi) {
        int m = m0 + wr * 64 + mi * 16 + q15;
        int bb = m >> 11, s = m & 2047;
        size_t bhs = (size_t)(bb * 16 + h) * 2048 + s;
        float v0 = acc[mi][ni][0] + bi.x, v1 = acc[mi][ni][1] + bi.y;
        float v2 = acc[mi][ni][2] + bi.z, v3 = acc[mi][ni][3] + bi.w;
        size_t addr;
        if (P == 0) {
          const float qs = 0.125f * LOG2E;           // fold 1/sqrt(HD), log2(e)
          v0 *= qs; v1 *= qs; v2 *= qs; v3 *= qs;
          addr = bhs * 64 + dbase;
        } else {
          int pos = (((dbase >> 3) ^ (s & 7)) << 3) | (dbase & 7);   // K 16B-unit swz
          addr = 4194304 + bhs * 64 + pos;
        }
        *(ushort4*)&qkv[addr] = make_ushort4(f2bf(v0), f2bf(v1), f2bf(v2), f2bf(v3));
      }
    }
  } else {
    float biasv[4];
#pragma unroll
    for (int ni = 0; ni < 4; ++ni) biasv[ni] = bias[n0 + wc * 64 + ni * 16 + q15];
#pragma unroll
    for (int mi = 0; mi < 4; ++mi) {
      int mbase = m0 + wr * 64 + mi * 16 + g * 4;    // r -> consecutive s
      int bb = mbase >> 11, sbase = mbase & 2047;
      int sr = sbase & 31;
      int cba = (((sr >> 4) & 1) << 2) | (((sr >> 2) & 3) << 3);     // P-frag col perm
      int sp = (sbase & 32) | cba;
#pragma unroll
      for (int ni = 0; ni < 4; ++ni) {
        int n = n0 + wc * 64 + ni * 16 + q15;
        int d = n & 63, h = n >> 6;
        int spp = (((sp >> 3) ^ (d & 7)) << 3) | (sp & 7);           // 16B-unit swz
        size_t addr = 8388608 + ((size_t)(bb * 16 + h) * 64 + d) * 2048 + (sbase & ~63) + spp;
        *(ushort4*)&qkv[addr] = make_ushort4(
            f2bf(acc[mi][ni][0] + biasv[ni]), f2bf(acc[mi][ni][1] + biasv[ni]),
            f2bf(acc[mi][ni][2] + biasv[ni]), f2bf(acc[mi][ni][3] + biasv[ni]));
      }
    }
  }
}

__global__ __launch_bounds__(256) void qkv_gemm(
    const u16* __restrict__ xbf, const u16* __restrict__ wbf,
    const float* __restrict__ bq, const float* __restrict__ bk, const float* __restrict__ bv,
    u16* __restrict__ qkv) {
  __shared__ __align__(16) u16 As[3 * 4096];
  __shared__ __align__(16) u16 Bs[3 * 4096];
  switch (blockIdx.z) {
    case 0: gemm_body<0>(xbf, wbf, bq, qkv, As, Bs); break;
    case 1: gemm_body<1>(xbf, wbf, bk, qkv, As, Bs); break;
    default: gemm_body<2>(xbf, wbf, bv, qkv, As, Bs); break;
  }
}

// ---------------- Kernel 3: causal flash attention, 3-buffer counted-vmcnt ----------------
__global__ __launch_bounds__(256, 2) void attn_kernel(
    const u16* __restrict__ qkv, const float* __restrict__ amask, float* __restrict__ out) {
  const int bid = blockIdx.x;
  const int bh = (bid & 7) * 4 + ((bid >> 3) & 3);   // 4 bh per XCD -> K/V L2-resident
  const int pi = bid >> 5;                           // 0..15 pair index
  const int b = bh >> 4, h = bh & 15;
  const int tid = threadIdx.x, lane = tid & 63, w = tid >> 6;
  const int g = lane >> 4, ql = lane & 15;
  const u16* Qb = qkv + (size_t)bh * 131072;
  const u16* Kb = qkv + 4194304 + (size_t)bh * 131072;
  const u16* Vb = qkv + 8388608 + (size_t)bh * 131072;   // [64][2048] transposed
  __shared__ __align__(16) u16 Ks[3][64][64];
  __shared__ __align__(16) u16 Vs[3][64][64];
  __shared__ __align__(16) float MaskL[2048];
  const f32x4 fzero = {0.f, 0.f, 0.f, 0.f};

  // one-time mask preload (so per-tile STAGE is exactly 4 VMEM ops/wave)
  {
    int o = tid * 4;
#pragma unroll
    for (int i = 0; i < 2; ++i) {
      float4 mv = *(const float4*)&amask[b * 2048 + o + i * 1024];
      mv.x *= LOG2E; mv.y *= LOG2E; mv.z *= LOG2E; mv.w *= LOG2E;
      *(float4*)&MaskL[o + i * 1024] = mv;
    }
  }
  LGKM0();
  SCHED0();

  auto STAGE = [&](int nb, int kb) {
#pragma unroll
    for (int j = 0; j < 2; ++j) {
      int rl = w * 16 + j * 8 + (lane >> 3);
      gload_lds16(Kb + (size_t)(kb + rl) * 64 + (lane & 7) * 8, &Ks[nb][w * 16 + j * 8][0]);
      gload_lds16(Vb + (size_t)rl * 2048 + kb + (lane & 7) * 8, &Vs[nb][w * 16 + j * 8][0]);
    }
  };

#pragma unroll 1
  for (int ph = 0; ph < 2; ++ph) {
    const int qt = ph ? (31 - pi) : pi;
    const int qw = qt * 64 + w * 16;
    const int q  = qw + ql;
    bf16x8 qf[2];
#pragma unroll
    for (int ks = 0; ks < 2; ++ks)
      qf[ks] = *(const bf16x8*)&Qb[(size_t)q * 64 + ks * 32 + g * 8];
    f32x4 acc[4];
#pragma unroll
    for (int dt = 0; dt < 4; ++dt) acc[dt] = fzero;
    float mrun = -1e30f, lrun = 0.f;
    const int nt = qt + 1;

    STAGE(0, 0);
    STAGE(1, 64);
    int c0 = 0, c1 = 1, c2 = 2;
#pragma unroll 1
    for (int t = 0; t < nt; ++t) {
      if (t + 1 < nt) WAITV4(); else WAITV0();
      SCHED0();
      __builtin_amdgcn_s_barrier();
      const int kb = t * 64;
      if (t + 2 < nt) STAGE(c2, kb + 128);
      // ---- QK^T: S^T, lane owns q=ql; keys k16*16 + g*4 + r ----
      f32x4 st[4];
#pragma unroll
      for (int k16 = 0; k16 < 4; ++k16) st[k16] = fzero;
      __builtin_amdgcn_s_setprio(1);
#pragma unroll
      for (int k16 = 0; k16 < 4; ++k16) {
        bf16x8 kf0 = *(const bf16x8*)&Ks[c0][k16 * 16 + ql][(g ^ (ql & 7)) * 8];
        bf16x8 kf1 = *(const bf16x8*)&Ks[c0][k16 * 16 + ql][((4 + g) ^ (ql & 7)) * 8];
        st[k16] = __builtin_amdgcn_mfma_f32_16x16x32_bf16(kf0, qf[0], st[k16], 0, 0, 0);
        st[k16] = __builtin_amdgcn_mfma_f32_16x16x32_bf16(kf1, qf[1], st[k16], 0, 0, 0);
      }
      __builtin_amdgcn_s_setprio(0);
      f32x4 mk[4];
#pragma unroll
      for (int k16 = 0; k16 < 4; ++k16) mk[k16] = *(const f32x4*)&MaskL[kb + k16 * 16 + g * 4];
      // ---- online softmax (log2 domain, defer-max THR=8) ----
      const bool needm = (t == nt - 1);            // diagonal tile only (wave-uniform)
      float sc[16], pmax = -1e30f;
#pragma unroll
      for (int k16 = 0; k16 < 4; ++k16)
#pragma unroll
        for (int r = 0; r < 4; ++r) {
          float sv = st[k16][r] + mk[k16][r];
          if (needm) { int key = kb + k16 * 16 + g * 4 + r; sv = (key > q) ? -1e30f : sv; }
          sc[k16 * 4 + r] = sv;
          pmax = fmaxf(pmax, sv);
        }
      if (!__all(pmax <= mrun + 8.f)) {            // rescale only when max grows
        float pm = fmaxf(pmax, __shfl_xor(pmax, 16, 64));
        pm = fmaxf(pm, __shfl_xor(pm, 32, 64));
        const float mt = fmaxf(mrun, pm);
        const float scale = EXP2(mrun - mt);
        lrun *= scale;
#pragma unroll
        for (int dt = 0; dt < 4; ++dt) acc[dt] *= scale;
        mrun = mt;
      }
      float pv[16], ps = 0.f;
#pragma unroll
      for (int i = 0; i < 16; ++i) { pv[i] = EXP2(sc[i] - mrun); ps += pv[i]; }
      lrun += ps;                                  // per-lane partial; reduced in epilogue
      bf16x8 pfv[2];
#pragma unroll
      for (int ksub = 0; ksub < 2; ++ksub)
#pragma unroll
        for (int j = 0; j < 4; ++j) {
          pfv[ksub][j]     = (__bf16)pv[ksub * 8 + j];
          pfv[ksub][4 + j] = (__bf16)pv[ksub * 8 + 4 + j];
        }
      // ---- PV: acc^T[d][q] += V^T P ----
      __builtin_amdgcn_s_setprio(1);
#pragma unroll
      for (int dt = 0; dt < 4; ++dt)
#pragma unroll
        for (int ksub = 0; ksub < 2; ++ksub) {
          bf16x8 vf = *(const bf16x8*)&Vs[c0][dt * 16 + ql][((ksub * 4 + g) ^ (ql & 7)) * 8];
          acc[dt] = __builtin_amdgcn_mfma_f32_16x16x32_bf16(vf, pfv[ksub], acc[dt], 0, 0, 0);
        }
      __builtin_amdgcn_s_setprio(0);
      int tmp = c0; c0 = c1; c1 = c2; c2 = tmp;
    }

    float lsum = lrun;
    lsum += __shfl_xor(lsum, 16, 64);
    lsum += __shfl_xor(lsum, 32, 64);
    const float inv = 1.f / lsum;
#pragma unroll
    for (int dt = 0; dt < 4; ++dt) {
      f32x4 o = acc[dt] * inv;
      *(f32x4*)&out[((size_t)b * 2048 + q) * 1024 + h * 64 + dt * 16 + g * 4] = o;
    }
    __syncthreads();   // drain + protect K/V buffers before next phase re-stages
  }
}

// ---------------- launch ----------------
extern "C" void kernel_launch(void* const* d_in, const int* in_sizes, int n_in,
                              void* d_out, int out_size, void* d_ws, size_t ws_size,
                              hipStream_t stream) {
  const float* x  = (const float*)d_in[0];
  const float* am = (const float*)d_in[1];
  const float* Wq = (const float*)d_in[2];
  const float* bq = (const float*)d_in[3];
  const float* Aq = (const float*)d_in[4];
  const float* Bq = (const float*)d_in[5];
  const float* Wk = (const float*)d_in[6];
  const float* bk = (const float*)d_in[7];
  const float* Ak = (const float*)d_in[8];
  const float* Bk = (const float*)d_in[9];
  const float* Wv = (const float*)d_in[10];
  const float* bv = (const float*)d_in[11];
  const float* Av = (const float*)d_in[12];
  const float* Bv = (const float*)d_in[13];
  float* out = (float*)d_out;

  u16* xbf   = (u16*)d_ws;                     // 4194304 u16 = 8 MB
  u16* wbf   = xbf + 4194304;                  // 3145728 u16 = 6 MB
  u16* qkv   = wbf + 3145728;                  // 12582912 u16 = 24 MB

  cvt_kernel<<<7168, 256, 0, stream>>>(x, Wq, Wk, Wv, Aq, Ak, Av, Bq, Bk, Bv, xbf, wbf);
  qkv_gemm<<<dim3(8, 32, 3), 256, 0, stream>>>(xbf, wbf, bq, bk, bv, qkv);
  attn_kernel<<<512, 256, 0, stream>>>(qkv, am, out);
}

// Round 6
// 89.308 us; speedup vs baseline: 1.9324x; 1.0027x over previous
//
#include <hip/hip_runtime.h>
#include <stdint.h>

// Problem constants
#define B_ 2
#define S_ 2048
#define H_ 1024
#define NH_ 16
#define HD_ 64
#define M_ 4096            // B*S
#define LOG2E 1.44269504089f

typedef unsigned short u16;
typedef __bf16 bf16x8 __attribute__((ext_vector_type(8)));
typedef float  f32x4  __attribute__((ext_vector_type(4)));

#if __has_builtin(__builtin_amdgcn_exp2f)
#define EXP2(x) __builtin_amdgcn_exp2f(x)
#else
#define EXP2(x) exp2f(x)
#endif

#define WAITV4() asm volatile("s_waitcnt vmcnt(4)" ::: "memory")
#define WAITV0() asm volatile("s_waitcnt vmcnt(0)" ::: "memory")
#define LGKM0()  asm volatile("s_waitcnt lgkmcnt(0)" ::: "memory")
#define SCHED0() __builtin_amdgcn_sched_barrier(0)

__device__ inline u16 f2bf(float f) {
  union { float f; uint32_t u; } a; a.f = f;
  uint32_t r = a.u + 0x7FFFu + ((a.u >> 16) & 1u);
  return (u16)(r >> 16);
}

__device__ inline void gload_lds16(const void* g, void* l) {
  __builtin_amdgcn_global_load_lds((const __attribute__((address_space(1))) void*)g,
                                   (__attribute__((address_space(3))) void*)l, 16, 0, 0);
}

// ---------------- Kernel 1: f32 -> bf16 convert; W' = W + 4*LB*A folded (exact) ----------------
__global__ __launch_bounds__(256) void cvt_kernel(
    const float* __restrict__ x,
    const float* __restrict__ wq, const float* __restrict__ wk, const float* __restrict__ wv,
    const float* __restrict__ Aq, const float* __restrict__ Ak, const float* __restrict__ Av,
    const float* __restrict__ LBq, const float* __restrict__ LBk, const float* __restrict__ LBv,
    u16* __restrict__ xbf, u16* __restrict__ wbf) {
  const int XN = M_ * H_;            // 4194304
  const int WN = H_ * H_;            // 1048576
  int idx = (blockIdx.x * 256 + threadIdx.x) * 4;   // grid sized exactly: (XN+3WN)/4/256 blocks
  if (idx < XN) {
    float4 v = *(const float4*)(x + idx);
    *(ushort4*)(xbf + idx) = make_ushort4(f2bf(v.x), f2bf(v.y), f2bf(v.z), f2bf(v.w));
  } else {
    int j = idx - XN; int p = j >> 20; int off = j & (WN - 1);
    const float* W  = (p == 0) ? wq : (p == 1 ? wk : wv);
    const float* A  = (p == 0) ? Aq : (p == 1 ? Ak : Av);
    const float* LB = (p == 0) ? LBq : (p == 1 ? LBk : LBv);
    int n = off >> 10, k = off & 1023;
    float4 v  = *(const float4*)(W + off);
    f32x4 lb  = *(const f32x4*)&LB[n * 4];
    float4 a0 = *(const float4*)(A + k);
    float4 a1 = *(const float4*)(A + 1024 + k);
    float4 a2 = *(const float4*)(A + 2048 + k);
    float4 a3 = *(const float4*)(A + 3072 + k);
    v.x += 4.f * (lb.x * a0.x + lb.y * a1.x + lb.z * a2.x + lb.w * a3.x);
    v.y += 4.f * (lb.x * a0.y + lb.y * a1.y + lb.z * a2.y + lb.w * a3.y);
    v.z += 4.f * (lb.x * a0.z + lb.y * a1.z + lb.z * a2.z + lb.w * a3.z);
    v.w += 4.f * (lb.x * a0.w + lb.y * a1.w + lb.z * a2.w + lb.w * a3.w);
    *(ushort4*)(wbf + (p << 20) + off) = make_ushort4(f2bf(v.x), f2bf(v.y), f2bf(v.z), f2bf(v.w));
  }
}

// ---------------- Kernel 2: fused QKV GEMM, 3-buffer counted-vmcnt pipeline ----------------
template<int P>
__device__ __forceinline__ void gemm_body(
    const u16* __restrict__ xbf, const u16* __restrict__ wbf,
    const float* __restrict__ bias, u16* __restrict__ qkv,
    u16* __restrict__ As, u16* __restrict__ Bs) {
  const int n0 = blockIdx.x * 128;
  const int m0 = blockIdx.y * 128;
  const u16* Wp = wbf + (P << 20);
  const int tid = threadIdx.x, lane = tid & 63, w = tid >> 6;
  const int g = lane >> 4, q15 = lane & 15;
  const int wr = w >> 1, wc = w & 1;
  const f32x4 fzero = {0.f, 0.f, 0.f, 0.f};
  f32x4 acc[4][4];
#pragma unroll
  for (int mi = 0; mi < 4; ++mi)
#pragma unroll
    for (int ni = 0; ni < 4; ++ni) acc[mi][ni] = fzero;
  const int srow = lane >> 2;

  auto STAGE = [&](int buf, int k0) {
#pragma unroll
    for (int j = 0; j < 2; ++j) {
      int c = w * 2 + j;
      int row = c * 16 + srow;
      int uu = (lane & 3) ^ ((row >> 1) & 3);     // pre-swizzled global 16B-unit
      gload_lds16(xbf + (size_t)(m0 + row) * 1024 + k0 + uu * 8, As + buf * 4096 + c * 512);
      gload_lds16(Wp  + (size_t)(n0 + row) * 1024 + k0 + uu * 8, Bs + buf * 4096 + c * 512);
    }
  };

  STAGE(0, 0);
  STAGE(1, 32);
  int c0 = 0, c1 = 1, c2 = 2;
#pragma unroll 1
  for (int t = 0; t < 32; ++t) {
    if (t < 31) WAITV4(); else WAITV0();   // own stage(t) landed; stage(t+1) stays in flight
    SCHED0();
    __builtin_amdgcn_s_barrier();          // all waves' stage(t) landed; buf[c2] reads done
    if (t + 2 < 32) STAGE(c2, (t + 2) * 32);
    const u16* Ab = As + c0 * 4096;
    const u16* Bb = Bs + c0 * 4096;
    bf16x8 af[4], bfr[4];
#pragma unroll
    for (int mi = 0; mi < 4; ++mi) {
      int r = wr * 64 + mi * 16 + q15;
      af[mi] = *(const bf16x8*)&Ab[r * 32 + ((g ^ ((r >> 1) & 3)) * 8)];
    }
#pragma unroll
    for (int ni = 0; ni < 4; ++ni) {
      int r = wc * 64 + ni * 16 + q15;
      bfr[ni] = *(const bf16x8*)&Bb[r * 32 + ((g ^ ((r >> 1) & 3)) * 8)];
    }
    __builtin_amdgcn_s_setprio(1);
#pragma unroll
    for (int mi = 0; mi < 4; ++mi)
#pragma unroll
      for (int ni = 0; ni < 4; ++ni) {
        if (P == 2)
          acc[mi][ni] = __builtin_amdgcn_mfma_f32_16x16x32_bf16(af[mi], bfr[ni], acc[mi][ni], 0, 0, 0);
        else
          acc[mi][ni] = __builtin_amdgcn_mfma_f32_16x16x32_bf16(bfr[ni], af[mi], acc[mi][ni], 0, 0, 0);
      }
    __builtin_amdgcn_s_setprio(0);
    int tmp = c0; c0 = c1; c1 = c2; c2 = tmp;
  }

  // ---- epilogue: bias + vectorized ushort4 stores ----
  if (P != 2) {
#pragma unroll
    for (int ni = 0; ni < 4; ++ni) {
      int nb = n0 + wc * 64 + ni * 16 + g * 4;       // 4-aligned
      f32x4 bi = *(const f32x4*)&bias[nb];
      int h = nb >> 6, dbase = nb & 63;
#pragma unroll
      for (int mi = 0; mi < 4; ++mi) {
        int m = m0 + wr * 64 + mi * 16 + q15;
        int bb = m >> 11, s = m & 2047;
        size_t bhs = (size_t)(bb * 16 + h) * 2048 + s;
        float v0 = acc[mi][ni][0] + bi.x, v1 = acc[mi][ni][1] + bi.y;
        float v2 = acc[mi][ni][2] + bi.z, v3 = acc[mi][ni][3] + bi.w;
        size_t addr;
        if (P == 0) {
          const float qs = 0.125f * LOG2E;           // fold 1/sqrt(HD), log2(e)
          v0 *= qs; v1 *= qs; v2 *= qs; v3 *= qs;
          addr = bhs * 64 + dbase;
        } else {
          int pos = (((dbase >> 3) ^ (s & 7)) << 3) | (dbase & 7);   // K 16B-unit swz
          addr = 4194304 + bhs * 64 + pos;
        }
        *(ushort4*)&qkv[addr] = make_ushort4(f2bf(v0), f2bf(v1), f2bf(v2), f2bf(v3));
      }
    }
  } else {
    float biasv[4];
#pragma unroll
    for (int ni = 0; ni < 4; ++ni) biasv[ni] = bias[n0 + wc * 64 + ni * 16 + q15];
#pragma unroll
    for (int mi = 0; mi < 4; ++mi) {
      int mbase = m0 + wr * 64 + mi * 16 + g * 4;    // r -> consecutive s
      int bb = mbase >> 11, sbase = mbase & 2047;
      int sr = sbase & 31;
      int cba = (((sr >> 4) & 1) << 2) | (((sr >> 2) & 3) << 3);     // P-frag col perm
      int sp = (sbase & 32) | cba;
#pragma unroll
      for (int ni = 0; ni < 4; ++ni) {
        int n = n0 + wc * 64 + ni * 16 + q15;
        int d = n & 63, h = n >> 6;
        int spp = (((sp >> 3) ^ (d & 7)) << 3) | (sp & 7);           // 16B-unit swz
        size_t addr = 8388608 + ((size_t)(bb * 16 + h) * 64 + d) * 2048 + (sbase & ~63) + spp;
        *(ushort4*)&qkv[addr] = make_ushort4(
            f2bf(acc[mi][ni][0] + biasv[ni]), f2bf(acc[mi][ni][1] + biasv[ni]),
            f2bf(acc[mi][ni][2] + biasv[ni]), f2bf(acc[mi][ni][3] + biasv[ni]));
      }
    }
  }
}

__global__ __launch_bounds__(256) void qkv_gemm(
    const u16* __restrict__ xbf, const u16* __restrict__ wbf,
    const float* __restrict__ bq, const float* __restrict__ bk, const float* __restrict__ bv,
    u16* __restrict__ qkv) {
  __shared__ __align__(16) u16 As[3 * 4096];
  __shared__ __align__(16) u16 Bs[3 * 4096];
  switch (blockIdx.z) {
    case 0: gemm_body<0>(xbf, wbf, bq, qkv, As, Bs); break;
    case 1: gemm_body<1>(xbf, wbf, bk, qkv, As, Bs); break;
    default: gemm_body<2>(xbf, wbf, bv, qkv, As, Bs); break;
  }
}

// ---------------- Kernel 3: causal flash attention ----------------
// 1024 blocks (one 64-q tile each), long-qt-first, 4 bh per XCD. 2-buffer K/V
// (40 KB LDS incl mask) -> 4 blocks/CU resident; __launch_bounds__(256,4).
__global__ __launch_bounds__(256, 4) void attn_kernel(
    const u16* __restrict__ qkv, const float* __restrict__ amask, float* __restrict__ out) {
  const int bid = blockIdx.x;
  const int bh = (bid & 7) * 4 + ((bid >> 3) & 3);   // 4 bh per XCD -> K/V L2-resident
  const int qt = 31 - (bid >> 5);                    // long blocks first
  const int b = bh >> 4, h = bh & 15;
  const int tid = threadIdx.x, lane = tid & 63, w = tid >> 6;
  const int g = lane >> 4, ql = lane & 15;
  const u16* Qb = qkv + (size_t)bh * 131072;
  const u16* Kb = qkv + 4194304 + (size_t)bh * 131072;
  const u16* Vb = qkv + 8388608 + (size_t)bh * 131072;   // [64][2048] transposed
  __shared__ __align__(16) u16 Ks[2][64][64];
  __shared__ __align__(16) u16 Vs[2][64][64];
  __shared__ __align__(16) float MaskL[2048];
  const f32x4 fzero = {0.f, 0.f, 0.f, 0.f};

  // one-time mask preload (per-tile STAGE stays exactly 4 VMEM ops/wave)
  {
    int o = tid * 4;
#pragma unroll
    for (int i = 0; i < 2; ++i) {
      float4 mv = *(const float4*)&amask[b * 2048 + o + i * 1024];
      mv.x *= LOG2E; mv.y *= LOG2E; mv.z *= LOG2E; mv.w *= LOG2E;
      *(float4*)&MaskL[o + i * 1024] = mv;
    }
  }
  LGKM0();
  SCHED0();

  auto STAGE = [&](int nb, int kb) {
#pragma unroll
    for (int j = 0; j < 2; ++j) {
      int rl = w * 16 + j * 8 + (lane >> 3);
      gload_lds16(Kb + (size_t)(kb + rl) * 64 + (lane & 7) * 8, &Ks[nb][w * 16 + j * 8][0]);
      gload_lds16(Vb + (size_t)rl * 2048 + kb + (lane & 7) * 8, &Vs[nb][w * 16 + j * 8][0]);
    }
  };

  const int qw = qt * 64 + w * 16;
  const int q  = qw + ql;
  bf16x8 qf[2];
#pragma unroll
  for (int ks = 0; ks < 2; ++ks)
    qf[ks] = *(const bf16x8*)&Qb[(size_t)q * 64 + ks * 32 + g * 8];
  f32x4 acc[4];
#pragma unroll
  for (int dt = 0; dt < 4; ++dt) acc[dt] = fzero;
  float mrun = -1e30f, lrun = 0.f;
  const int nt = qt + 1;

  STAGE(0, 0);
#pragma unroll 1
  for (int t = 0; t < nt; ++t) {
    WAITV0();                       // own stage(t) landed (stage(t+1) not yet issued)
    SCHED0();
    __builtin_amdgcn_s_barrier();   // all waves staged(t); buf[(t+1)&1] reads done
    const int kb = t * 64;
    if (t + 1 < nt) STAGE((t + 1) & 1, kb + 64);
    const int cb = t & 1;
    // ---- QK^T: S^T, lane owns q=ql; keys k16*16 + g*4 + r ----
    f32x4 st[4];
#pragma unroll
    for (int k16 = 0; k16 < 4; ++k16) st[k16] = fzero;
    __builtin_amdgcn_s_setprio(1);
#pragma unroll
    for (int k16 = 0; k16 < 4; ++k16) {
      bf16x8 kf0 = *(const bf16x8*)&Ks[cb][k16 * 16 + ql][(g ^ (ql & 7)) * 8];
      bf16x8 kf1 = *(const bf16x8*)&Ks[cb][k16 * 16 + ql][((4 + g) ^ (ql & 7)) * 8];
      st[k16] = __builtin_amdgcn_mfma_f32_16x16x32_bf16(kf0, qf[0], st[k16], 0, 0, 0);
      st[k16] = __builtin_amdgcn_mfma_f32_16x16x32_bf16(kf1, qf[1], st[k16], 0, 0, 0);
    }
    __builtin_amdgcn_s_setprio(0);
    f32x4 mk[4];
#pragma unroll
    for (int k16 = 0; k16 < 4; ++k16) mk[k16] = *(const f32x4*)&MaskL[kb + k16 * 16 + g * 4];
    // ---- online softmax (log2 domain, defer-max THR=8) ----
    const bool needm = (t == nt - 1);            // diagonal tile only (wave-uniform)
    float sc[16], pmax = -1e30f;
#pragma unroll
    for (int k16 = 0; k16 < 4; ++k16)
#pragma unroll
      for (int r = 0; r < 4; ++r) {
        float sv = st[k16][r] + mk[k16][r];
        if (needm) { int key = kb + k16 * 16 + g * 4 + r; sv = (key > q) ? -1e30f : sv; }
        sc[k16 * 4 + r] = sv;
        pmax = fmaxf(pmax, sv);
      }
    if (!__all(pmax <= mrun + 8.f)) {            // rescale only when max grows
      float pm = fmaxf(pmax, __shfl_xor(pmax, 16, 64));
      pm = fmaxf(pm, __shfl_xor(pm, 32, 64));
      const float mt = fmaxf(mrun, pm);
      const float scale = EXP2(mrun - mt);
      lrun *= scale;
#pragma unroll
      for (int dt = 0; dt < 4; ++dt) acc[dt] *= scale;
      mrun = mt;
    }
    float pv[16], ps = 0.f;
#pragma unroll
    for (int i = 0; i < 16; ++i) { pv[i] = EXP2(sc[i] - mrun); ps += pv[i]; }
    lrun += ps;                                  // per-lane partial; reduced in epilogue
    bf16x8 pfv[2];
#pragma unroll
    for (int ksub = 0; ksub < 2; ++ksub)
#pragma unroll
      for (int j = 0; j < 4; ++j) {
        pfv[ksub][j]     = (__bf16)pv[ksub * 8 + j];
        pfv[ksub][4 + j] = (__bf16)pv[ksub * 8 + 4 + j];
      }
    // ---- PV: acc^T[d][q] += V^T P ----
    __builtin_amdgcn_s_setprio(1);
#pragma unroll
    for (int dt = 0; dt < 4; ++dt)
#pragma unroll
      for (int ksub = 0; ksub < 2; ++ksub) {
        bf16x8 vf = *(const bf16x8*)&Vs[cb][dt * 16 + ql][((ksub * 4 + g) ^ (ql & 7)) * 8];
        acc[dt] = __builtin_amdgcn_mfma_f32_16x16x32_bf16(vf, pfv[ksub], acc[dt], 0, 0, 0);
      }
    __builtin_amdgcn_s_setprio(0);
  }

  float lsum = lrun;
  lsum += __shfl_xor(lsum, 16, 64);
  lsum += __shfl_xor(lsum, 32, 64);
  const float inv = 1.f / lsum;
#pragma unroll
  for (int dt = 0; dt < 4; ++dt) {
    f32x4 o = acc[dt] * inv;
    *(f32x4*)&out[((size_t)b * 2048 + q) * 1024 + h * 64 + dt * 16 + g * 4] = o;
  }
}

// ---------------- launch ----------------
extern "C" void kernel_launch(void* const* d_in, const int* in_sizes, int n_in,
                              void* d_out, int out_size, void* d_ws, size_t ws_size,
                              hipStream_t stream) {
  const float* x  = (const float*)d_in[0];
  const float* am = (const float*)d_in[1];
  const float* Wq = (const float*)d_in[2];
  const float* bq = (const float*)d_in[3];
  const float* Aq = (const float*)d_in[4];
  const float* Bq = (const float*)d_in[5];
  const float* Wk = (const float*)d_in[6];
  const float* bk = (const float*)d_in[7];
  const float* Ak = (const float*)d_in[8];
  const float* Bk = (const float*)d_in[9];
  const float* Wv = (const float*)d_in[10];
  const float* bv = (const float*)d_in[11];
  const float* Av = (const float*)d_in[12];
  const float* Bv = (const float*)d_in[13];
  float* out = (float*)d_out;

  u16* xbf   = (u16*)d_ws;                     // 4194304 u16 = 8 MB
  u16* wbf   = xbf + 4194304;                  // 3145728 u16 = 6 MB
  u16* qkv   = wbf + 3145728;                  // 12582912 u16 = 24 MB

  cvt_kernel<<<7168, 256, 0, stream>>>(x, Wq, Wk, Wv, Aq, Ak, Av, Bq, Bk, Bv, xbf, wbf);
  qkv_gemm<<<dim3(8, 32, 3), 256, 0, stream>>>(xbf, wbf, bq, bk, bv, qkv);
  attn_kernel<<<1024, 256, 0, stream>>>(qkv, am, out);
}